// Round 13
// baseline (954.494 us; speedup 1.0000x reference)
//
#include <hip/hip_runtime.h>

#define DI __device__ __forceinline__

constexpr float BN_EPS_C = 1e-5f;
constexpr float LN_EPS_C = 1e-5f;

typedef _Float16 half8 __attribute__((ext_vector_type(8)));
typedef float f32x4 __attribute__((ext_vector_type(4)));

// ---------------- workspace layout (BYTE offsets), peak ~199.34 MB ----------------
constexpr size_t B_H0   = 0;
constexpr size_t B_H1   = 8388608;
constexpr size_t B_H2   = 25165824;      // f16 [4][256][256][256] = 134,217,728
constexpr size_t B_Q    = 25165824;
constexpr size_t B_V    = 58720256;
constexpr size_t B_KT   = 75497472;
constexpr size_t B_ATT  = 92274688;
constexpr size_t B_LNB  = 25165824;
constexpr size_t B_TOK  = 159383552;
constexpr size_t B_WP1  = 185597952;
constexpr size_t B_WP2  = 185745408;
constexpr size_t B_WP3  = 186335232;
constexpr size_t B_QKVT = 192888832;
constexpr size_t B_OWT  = 195346432;
constexpr size_t B_QL   = 196165632;
constexpr size_t B_KL   = 196689920;
constexpr size_t B_KLH  = 197214208;
constexpr size_t B_A2   = 197476352;
constexpr size_t B_W2T  = 198524928;
constexpr size_t B_A3V  = 198787072;
constexpr size_t B_SCAL = 199311360;
constexpr size_t B_HWH  = 199311424;

// ---------------- helpers ----------------
template <int LP, int RP>
DI void mm16v(const float* L, const float* R, int r0, int c0, float reg[4][4]) {
  #pragma unroll
  for (int i = 0; i < 4; ++i)
    #pragma unroll
    for (int j = 0; j < 4; ++j) reg[i][j] = 0.f;
  #pragma unroll 4
  for (int dd = 0; dd < 64; dd += 4) {
    f32x4 l[4], rv[4];
    #pragma unroll
    for (int i = 0; i < 4; ++i)
      l[i] = *reinterpret_cast<const f32x4*>(&L[(size_t)(r0 + i) * LP + dd]);
    #pragma unroll
    for (int u = 0; u < 4; ++u)
      rv[u] = *reinterpret_cast<const f32x4*>(&R[(size_t)(dd + u) * RP + c0]);
    #pragma unroll
    for (int i = 0; i < 4; ++i)
      #pragma unroll
      for (int u = 0; u < 4; ++u)
        #pragma unroll
        for (int j = 0; j < 4; ++j)
          reg[i][j] = fmaf(l[i][u], rv[u][j], reg[i][j]);
  }
}

// ---------------- mega-pack ----------------
__global__ void k_pack_all(
    const float* __restrict__ w1, const float* __restrict__ w2c, const float* __restrict__ w3,
    const float* __restrict__ qkvw, const float* __restrict__ outw, const float* __restrict__ headw,
    _Float16* __restrict__ wp1, _Float16* __restrict__ wp2, _Float16* __restrict__ wp3,
    _Float16* __restrict__ qkvT, _Float16* __restrict__ owT, _Float16* __restrict__ hwh,
    float* __restrict__ scal) {
  size_t i = (size_t)blockIdx.x * 256 + threadIdx.x;
  if (i < 73728) {
    int q = i % 9, ci = (i / 9) % 64, co = i / (9 * 64);
    wp1[((size_t)co * 9 + q) * 64 + ci] = (_Float16)w1[i];
  } else if (i < 368640) {
    size_t j = i - 73728;
    int q = j % 9, ci = (j / 9) % 128, co = j / (9 * 128);
    wp2[((size_t)co * 9 + q) * 128 + ci] = (_Float16)w2c[j];
  } else if (i < 3645440) {
    size_t j = i - 368640;
    int q = j % 16, ci = (j / 16) % 256, co = j / (16 * 256);
    wp3[((size_t)co * 16 + q) * 256 + ci] = (_Float16)w3[j];
  } else if (i < 4874240) {
    size_t j = i - 3645440;
    int n = j % 1536, k = j / 1536;
    qkvT[(size_t)n * 800 + k] = (_Float16)qkvw[j];
  } else if (i < 5283840) {
    size_t j = i - 4874240;
    int n = j % 800, k = j / 800;
    owT[(size_t)n * 512 + k] = (_Float16)outw[j];
  } else if (i < 5296640) {
    size_t j = i - 5283840;
    int n = j % 16, k = j / 16;
    hwh[(size_t)n * 800 + k] = (_Float16)headw[j];
  } else if (i < 5296642) {
    scal[i - 5296640] = 0.f;
  }
}

// ---------------- conv0 ----------------
__global__ __launch_bounds__(256) void k_conv0(
    const float* __restrict__ xb, const float* __restrict__ w0, const float* __restrict__ b0,
    const float* __restrict__ g0, const float* __restrict__ be0, const float* __restrict__ mu0,
    const float* __restrict__ var0, _Float16* __restrict__ h0) {
  const int t = threadIdx.x, co = t & 63, xg = t >> 6;
  const int y = blockIdx.x;
  const int x0 = blockIdx.y * 64 + xg * 16;
  float wreg[9];
  #pragma unroll
  for (int q = 0; q < 9; ++q) wreg[q] = w0[co * 9 + q];
  float s = g0[co] * rsqrtf(var0[co] + BN_EPS_C);
  float sh = fmaf(b0[co] - mu0[co], s, be0[co]);
  #pragma unroll 4
  for (int xl = 0; xl < 16; ++xl) {
    int xx = x0 + xl;
    float acc = 0.f;
    #pragma unroll
    for (int dy = 0; dy < 3; ++dy) {
      int yy = y + dy - 1;
      if ((unsigned)yy >= 256u) continue;
      #pragma unroll
      for (int dx = 0; dx < 3; ++dx) {
        int xi = xx + dx - 1;
        if ((unsigned)xi >= 256u) continue;
        acc = fmaf(wreg[dy * 3 + dx], xb[yy * 256 + xi], acc);
      }
    }
    float v = fmaxf(fmaf(acc, s, sh), 0.f);
    h0[((size_t)y * 256 + xx) * 64 + co] = (_Float16)v;
  }
}

// ------- staged implicit-im2col 3x3 conv GEMM: tile 128x128 (r11 single-deep) -----------
template <int CI>
__global__ __launch_bounds__(256) void k_convs(
    const _Float16* __restrict__ in, const _Float16* __restrict__ wp,
    const float* __restrict__ bias, const float* __restrict__ g, const float* __restrict__ be,
    const float* __restrict__ mu, const float* __restrict__ var,
    _Float16* __restrict__ out, int CO, int NCT) {
  __shared__ _Float16 Ab[2][128 * 40];
  __shared__ _Float16 Bb[2][128 * 40];
  constexpr int CPQ = CI / 32;
  constexpr int NCK = 9 * CPQ;
  const int t = threadIdx.x;
  const int bid = blockIdx.x;
  const int xcd = bid & 7, slot = bid >> 3;
  const int pj = slot / NCT, cc = slot % NCT;
  const int p = pj * 8 + xcd;
  const int r0 = p * 128, c0 = cc * 128;

  const int ma = t >> 2, kga = t & 3;
  int ry[2], rx[2];
  #pragma unroll
  for (int s = 0; s < 2; ++s) {
    int r = r0 + ma + s * 64;
    ry[s] = r >> 8;
    rx[s] = r & 255;
  }
  const _Float16* baseB[2];
  #pragma unroll
  for (int s = 0; s < 2; ++s)
    baseB[s] = wp + (size_t)(c0 + ma + s * 64) * 9 * CI + kga * 8;
  const int wo = ma * 40 + kga * 8;

  auto loadA = [&](int s, int ck) -> half8 {
    int q = ck / CPQ, coff = (ck % CPQ) * 32;
    int yy = ry[s] + q / 3 - 1;
    int xx = rx[s] + q % 3 - 1;
    half8 a = {};
    if ((unsigned)yy < 256u && (unsigned)xx < 256u)
      a = *reinterpret_cast<const half8*>(in + ((size_t)yy * 256 + xx) * CI + coff + kga * 8);
    return a;
  };

  {
    half8 a0 = loadA(0, 0), a1 = loadA(1, 0);
    half8 b0v = *reinterpret_cast<const half8*>(baseB[0]);
    half8 b1v = *reinterpret_cast<const half8*>(baseB[1]);
    *reinterpret_cast<half8*>(&Ab[0][wo]) = a0;
    *reinterpret_cast<half8*>(&Ab[0][wo + 2560]) = a1;
    *reinterpret_cast<half8*>(&Bb[0][wo]) = b0v;
    *reinterpret_cast<half8*>(&Bb[0][wo + 2560]) = b1v;
  }
  __syncthreads();

  const int w = t >> 6, lo = t & 15, hi = (t >> 4) & 3;
  const int wm = w >> 1, wn = w & 1;
  const int roA = (wm * 64 + lo) * 40 + 8 * hi;
  const int roB = (wn * 64 + lo) * 40 + 8 * hi;
  f32x4 acc[4][4] = {};

  for (int ck = 0; ck < NCK; ++ck) {
    const int cur = ck & 1;
    const bool more = (ck + 1 < NCK);
    half8 rA0, rA1, rB0, rB1;
    if (more) {
      rA0 = loadA(0, ck + 1);
      rA1 = loadA(1, ck + 1);
      rB0 = *reinterpret_cast<const half8*>(baseB[0] + (ck + 1) * 32);
      rB1 = *reinterpret_cast<const half8*>(baseB[1] + (ck + 1) * 32);
    }
    half8 af[4], bf[4];
    #pragma unroll
    for (int mi = 0; mi < 4; ++mi)
      af[mi] = *reinterpret_cast<const half8*>(&Ab[cur][roA + mi * 640]);
    #pragma unroll
    for (int ni = 0; ni < 4; ++ni)
      bf[ni] = *reinterpret_cast<const half8*>(&Bb[cur][roB + ni * 640]);
    #pragma unroll
    for (int mi = 0; mi < 4; ++mi)
      #pragma unroll
      for (int ni = 0; ni < 4; ++ni)
        acc[mi][ni] = __builtin_amdgcn_mfma_f32_16x16x32_f16(af[mi], bf[ni], acc[mi][ni], 0, 0, 0);
    if (more) {
      *reinterpret_cast<half8*>(&Ab[cur ^ 1][wo]) = rA0;
      *reinterpret_cast<half8*>(&Ab[cur ^ 1][wo + 2560]) = rA1;
      *reinterpret_cast<half8*>(&Bb[cur ^ 1][wo]) = rB0;
      *reinterpret_cast<half8*>(&Bb[cur ^ 1][wo + 2560]) = rB1;
    }
    __syncthreads();
  }

  #pragma unroll
  for (int ni = 0; ni < 4; ++ni) {
    int co = c0 + wn * 64 + ni * 16 + lo;
    float s = g[co] * rsqrtf(var[co] + BN_EPS_C);
    float sh = fmaf(bias[co] - mu[co], s, be[co]);
    #pragma unroll
    for (int mi = 0; mi < 4; ++mi)
      #pragma unroll
      for (int rr = 0; rr < 4; ++rr) {
        int row = r0 + wm * 64 + mi * 16 + hi * 4 + rr;
        float v = fmaxf(fmaf(acc[mi][ni][rr], s, sh), 0.f);
        out[(size_t)row * CO + co] = (_Float16)v;
      }
  }
}

// ---------------- conv3: staged GEMM 128x160, XCD-swizzled (r11 single-deep) ----------
__global__ __launch_bounds__(256) void k_c3(
    const _Float16* __restrict__ h2, const _Float16* __restrict__ wp3,
    const float* __restrict__ b3, const float* __restrict__ g3, const float* __restrict__ be3,
    const float* __restrict__ mu3, const float* __restrict__ var3,
    _Float16* __restrict__ tok) {
  __shared__ _Float16 Abuf[2][128 * 40];
  __shared__ _Float16 Bbuf[2][160 * 40];
  const int t = threadIdx.x;
  const int bid = blockIdx.x;
  const int xcd = bid & 7, slot = bid >> 3;
  const int pj = slot / 5, cc = slot % 5;
  const int p = pj * 8 + xcd;
  const int r0 = p * 128, c0 = cc * 160;
  const int img = r0 >> 12;
  const _Float16* h2i = h2 + (size_t)img * 16777216;

  const int ma = t >> 2, kga = t & 3;
  const _Float16* baseA[2];
  #pragma unroll
  for (int s = 0; s < 2; ++s) {
    int m = ma + s * 64;
    int r = r0 + m;
    int py = (r & 4095) >> 6, px = r & 63;
    baseA[s] = h2i + ((size_t)py * 1024 + px * 4) * 256 + kga * 8;
  }
  const _Float16* baseB[3];
  #pragma unroll
  for (int s = 0; s < 3; ++s) {
    int cb = ma + s * 64;
    baseB[s] = wp3 + (size_t)(c0 + (cb < 160 ? cb : 159)) * 4096 + kga * 8;
  }
  const int wo = ma * 40 + kga * 8;

  const int w = t >> 6, lo = t & 15, hi = (t >> 4) & 3;
  const int wm = w >> 1, wn = w & 1;
  const int roA = (wm * 64 + lo) * 40 + 8 * hi;
  const int roB = (wn * 80 + lo) * 40 + 8 * hi;

  f32x4 acc[4][5] = {};

  {
    half8 a0 = *reinterpret_cast<const half8*>(baseA[0]);
    half8 a1 = *reinterpret_cast<const half8*>(baseA[1]);
    half8 b0v = *reinterpret_cast<const half8*>(baseB[0]);
    half8 b1v = *reinterpret_cast<const half8*>(baseB[1]);
    *reinterpret_cast<half8*>(&Abuf[0][wo]) = a0;
    *reinterpret_cast<half8*>(&Abuf[0][wo + 2560]) = a1;
    *reinterpret_cast<half8*>(&Bbuf[0][wo]) = b0v;
    *reinterpret_cast<half8*>(&Bbuf[0][wo + 2560]) = b1v;
    if (t < 128) {
      half8 b2v = *reinterpret_cast<const half8*>(baseB[2]);
      *reinterpret_cast<half8*>(&Bbuf[0][wo + 5120]) = b2v;
    }
  }
  __syncthreads();

  for (int ck = 0; ck < 128; ++ck) {
    const int cur = ck & 1;
    const bool more = (ck + 1 < 128);
    half8 rA0, rA1, rB0, rB1, rB2;
    if (more) {
      const int kn = (ck + 1) << 5;
      const int q = kn >> 8, qk = kn & 255;
      const int aoff = (q >> 2) * 65536 + (q & 3) * 256 + qk;
      rA0 = *reinterpret_cast<const half8*>(baseA[0] + aoff);
      rA1 = *reinterpret_cast<const half8*>(baseA[1] + aoff);
      rB0 = *reinterpret_cast<const half8*>(baseB[0] + kn);
      rB1 = *reinterpret_cast<const half8*>(baseB[1] + kn);
      if (t < 128) rB2 = *reinterpret_cast<const half8*>(baseB[2] + kn);
    }
    half8 af[4], bf[5];
    #pragma unroll
    for (int mi = 0; mi < 4; ++mi)
      af[mi] = *reinterpret_cast<const half8*>(&Abuf[cur][roA + mi * 640]);
    #pragma unroll
    for (int ni = 0; ni < 5; ++ni)
      bf[ni] = *reinterpret_cast<const half8*>(&Bbuf[cur][roB + ni * 640]);
    #pragma unroll
    for (int mi = 0; mi < 4; ++mi)
      #pragma unroll
      for (int ni = 0; ni < 5; ++ni)
        acc[mi][ni] = __builtin_amdgcn_mfma_f32_16x16x32_f16(af[mi], bf[ni], acc[mi][ni], 0, 0, 0);
    if (more) {
      *reinterpret_cast<half8*>(&Abuf[cur ^ 1][wo]) = rA0;
      *reinterpret_cast<half8*>(&Abuf[cur ^ 1][wo + 2560]) = rA1;
      *reinterpret_cast<half8*>(&Bbuf[cur ^ 1][wo]) = rB0;
      *reinterpret_cast<half8*>(&Bbuf[cur ^ 1][wo + 2560]) = rB1;
      if (t < 128) *reinterpret_cast<half8*>(&Bbuf[cur ^ 1][wo + 5120]) = rB2;
    }
    __syncthreads();
  }

  #pragma unroll
  for (int ni = 0; ni < 5; ++ni) {
    int col = c0 + wn * 80 + ni * 16 + lo;
    float s = g3[col] * rsqrtf(var3[col] + BN_EPS_C);
    float sh = fmaf(b3[col] - mu3[col], s, be3[col]);
    #pragma unroll
    for (int mi = 0; mi < 4; ++mi)
      #pragma unroll
      for (int rr = 0; rr < 4; ++rr) {
        int row = r0 + wm * 64 + mi * 16 + hi * 4 + rr;
        float v = fmaxf(fmaf(acc[mi][ni][rr], s, sh), 0.f);
        tok[(size_t)row * 800 + col] = (_Float16)v;
      }
  }
}

// ---------------- qkv staged GEMM + fused landmarks; kT via LDS transpose -----------------
__global__ __launch_bounds__(256) void k_qkv_s(
    const _Float16* __restrict__ tok, const _Float16* __restrict__ qkvT,
    _Float16* __restrict__ qx, _Float16* __restrict__ kTg, _Float16* __restrict__ vx,
    float* __restrict__ ql, float* __restrict__ kl, _Float16* __restrict__ klh) {
  __shared__ _Float16 SH[20480];
  _Float16* AbP = SH;
  _Float16* BbP = SH + 10240;
  const int t = threadIdx.x;
  const int bid = blockIdx.x;
  const int xcd = bid & 7, slot = bid >> 3;
  const int pj = slot / 12, cc = slot % 12;
  const int p = pj * 8 + xcd;
  const int r0 = p * 128, c0 = cc * 128;

  const int ma = t >> 2, kga = t & 3;
  const _Float16* baseA[2];
  const _Float16* baseB[2];
  #pragma unroll
  for (int s = 0; s < 2; ++s) {
    baseA[s] = tok + (size_t)(r0 + ma + s * 64) * 800 + kga * 8;
    baseB[s] = qkvT + (size_t)(c0 + ma + s * 64) * 800 + kga * 8;
  }
  const int wo = ma * 40 + kga * 8;

  {
    half8 a0 = *reinterpret_cast<const half8*>(baseA[0]);
    half8 a1 = *reinterpret_cast<const half8*>(baseA[1]);
    half8 b0v = *reinterpret_cast<const half8*>(baseB[0]);
    half8 b1v = *reinterpret_cast<const half8*>(baseB[1]);
    *reinterpret_cast<half8*>(&AbP[wo]) = a0;
    *reinterpret_cast<half8*>(&AbP[wo + 2560]) = a1;
    *reinterpret_cast<half8*>(&BbP[wo]) = b0v;
    *reinterpret_cast<half8*>(&BbP[wo + 2560]) = b1v;
  }
  __syncthreads();

  const int w = t >> 6, lo = t & 15, hi = (t >> 4) & 3;
  const int wm = w >> 1, wn = w & 1;
  const int roA = (wm * 64 + lo) * 40 + 8 * hi;
  const int roB = (wn * 64 + lo) * 40 + 8 * hi;
  f32x4 acc[4][4] = {};

  for (int ck = 0; ck < 25; ++ck) {
    const int cur = ck & 1;
    const bool more = (ck + 1 < 25);
    half8 rA0, rA1, rB0, rB1;
    if (more) {
      const int kn = (ck + 1) * 32;
      rA0 = *reinterpret_cast<const half8*>(baseA[0] + kn);
      rA1 = *reinterpret_cast<const half8*>(baseA[1] + kn);
      rB0 = *reinterpret_cast<const half8*>(baseB[0] + kn);
      rB1 = *reinterpret_cast<const half8*>(baseB[1] + kn);
    }
    half8 af[4], bf[4];
    #pragma unroll
    for (int mi = 0; mi < 4; ++mi)
      af[mi] = *reinterpret_cast<const half8*>(&AbP[cur * 5120 + roA + mi * 640]);
    #pragma unroll
    for (int ni = 0; ni < 4; ++ni)
      bf[ni] = *reinterpret_cast<const half8*>(&BbP[cur * 5120 + roB + ni * 640]);
    #pragma unroll
    for (int mi = 0; mi < 4; ++mi)
      #pragma unroll
      for (int ni = 0; ni < 4; ++ni)
        acc[mi][ni] = __builtin_amdgcn_mfma_f32_16x16x32_f16(af[mi], bf[ni], acc[mi][ni], 0, 0, 0);
    if (more) {
      *reinterpret_cast<half8*>(&AbP[(cur ^ 1) * 5120 + wo]) = rA0;
      *reinterpret_cast<half8*>(&AbP[(cur ^ 1) * 5120 + wo + 2560]) = rA1;
      *reinterpret_cast<half8*>(&BbP[(cur ^ 1) * 5120 + wo]) = rB0;
      *reinterpret_cast<half8*>(&BbP[(cur ^ 1) * 5120 + wo + 2560]) = rB1;
    }
    __syncthreads();
  }

  const int seg = cc >> 2;
  const int b = r0 >> 12;
  const int m = ((r0 & 4095) >> 6) + wm;
  if (seg == 1) {
    #pragma unroll
    for (int ni = 0; ni < 4; ++ni) {
      int cl = wn * 64 + ni * 16 + lo;
      #pragma unroll
      for (int mi = 0; mi < 4; ++mi)
        #pragma unroll
        for (int rr = 0; rr < 4; ++rr) {
          int nl = wm * 64 + mi * 16 + hi * 4 + rr;
          SH[cl * 136 + nl] = (_Float16)acc[mi][ni][rr];
        }
    }
    __syncthreads();
    const int base_row = b * 512 + (cc & 3) * 128;
    const int base_n = (p & 31) * 128;
    #pragma unroll
    for (int e = t; e < 2048; e += 256) {
      int cl = e >> 4, ch = e & 15;
      half8 vvv = *reinterpret_cast<const half8*>(&SH[cl * 136 + ch * 8]);
      *reinterpret_cast<half8*>(&kTg[(size_t)(base_row + cl) * 4096 + base_n + ch * 8]) = vvv;
    }
  } else {
    const float scale = (seg == 0) ? 0.125f : 1.0f;
    _Float16* dst = (seg == 0) ? qx : vx;
    #pragma unroll
    for (int ni = 0; ni < 4; ++ni) {
      int cseg = (cc & 3) * 128 + wn * 64 + ni * 16 + lo;
      int h = cseg >> 6, d = cseg & 63;
      #pragma unroll
      for (int mi = 0; mi < 4; ++mi)
        #pragma unroll
        for (int rr = 0; rr < 4; ++rr) {
          int row = r0 + wm * 64 + mi * 16 + hi * 4 + rr;
          int nn = row & 4095;
          dst[((size_t)(b * 8 + h) * 4096 + nn) * 64 + d] = (_Float16)(acc[mi][ni][rr] * scale);
        }
    }
  }
  if (seg <= 1) {
    const float lscale = ((seg == 0) ? 0.125f : 1.0f) * (1.f / 64.f);
    #pragma unroll
    for (int ni = 0; ni < 4; ++ni) {
      float sum = 0.f;
      #pragma unroll
      for (int mi = 0; mi < 4; ++mi)
        #pragma unroll
        for (int rr = 0; rr < 4; ++rr) sum += acc[mi][ni][rr];
      sum += __shfl_xor(sum, 16);
      sum += __shfl_xor(sum, 32);
      if (hi == 0) {
        int cseg = (cc & 3) * 128 + wn * 64 + ni * 16 + lo;
        int h = cseg >> 6, d = cseg & 63;
        int bh = b * 8 + h;
        float lm = sum * lscale;
        if (seg == 0) {
          ql[((size_t)bh * 64 + m) * 64 + d] = lm;
        } else {
          kl[((size_t)bh * 64 + m) * 64 + d] = lm;
          klh[((size_t)bh * 64 + m) * 64 + d] = (_Float16)lm;
        }
      }
    }
  }
}

// ---------------- out-proj staged GEMM -> f16 lnb ----------------
__global__ __launch_bounds__(256) void k_op_s(
    const _Float16* __restrict__ attb, const _Float16* __restrict__ owT,
    const float* __restrict__ ob, _Float16* __restrict__ lnb) {
  __shared__ _Float16 Abuf[2][128 * 40];
  __shared__ _Float16 Bbuf[2][160 * 40];
  const int t = threadIdx.x;
  const int bid = blockIdx.x;
  const int xcd = bid & 7, slot = bid >> 3;
  const int pj = slot / 5, cc = slot % 5;
  const int p = pj * 8 + xcd;
  const int r0 = p * 128, c0 = cc * 160;

  const int ma = t >> 2, kga = t & 3;
  const _Float16* baseA[2];
  #pragma unroll
  for (int s = 0; s < 2; ++s)
    baseA[s] = attb + (size_t)(r0 + ma + s * 64) * 512 + kga * 8;
  const _Float16* baseB[3];
  #pragma unroll
  for (int s = 0; s < 3; ++s) {
    int cb = ma + s * 64;
    baseB[s] = owT + (size_t)(c0 + (cb < 160 ? cb : 159)) * 512 + kga * 8;
  }
  const int wo = ma * 40 + kga * 8;

  const int w = t >> 6, lo = t & 15, hi = (t >> 4) & 3;
  const int wm = w >> 1, wn = w & 1;
  const int roA = (wm * 64 + lo) * 40 + 8 * hi;
  const int roB = (wn * 80 + lo) * 40 + 8 * hi;

  f32x4 acc[4][5] = {};

  {
    half8 a0 = *reinterpret_cast<const half8*>(baseA[0]);
    half8 a1 = *reinterpret_cast<const half8*>(baseA[1]);
    half8 b0v = *reinterpret_cast<const half8*>(baseB[0]);
    half8 b1v = *reinterpret_cast<const half8*>(baseB[1]);
    *reinterpret_cast<half8*>(&Abuf[0][wo]) = a0;
    *reinterpret_cast<half8*>(&Abuf[0][wo + 2560]) = a1;
    *reinterpret_cast<half8*>(&Bbuf[0][wo]) = b0v;
    *reinterpret_cast<half8*>(&Bbuf[0][wo + 2560]) = b1v;
    if (t < 128) {
      half8 b2v = *reinterpret_cast<const half8*>(baseB[2]);
      *reinterpret_cast<half8*>(&Bbuf[0][wo + 5120]) = b2v;
    }
  }
  __syncthreads();

  for (int ck = 0; ck < 16; ++ck) {
    const int cur = ck & 1;
    const bool more = (ck + 1 < 16);
    half8 rA0, rA1, rB0, rB1, rB2;
    if (more) {
      const int kn = (ck + 1) << 5;
      rA0 = *reinterpret_cast<const half8*>(baseA[0] + kn);
      rA1 = *reinterpret_cast<const half8*>(baseA[1] + kn);
      rB0 = *reinterpret_cast<const half8*>(baseB[0] + kn);
      rB1 = *reinterpret_cast<const half8*>(baseB[1] + kn);
      if (t < 128) rB2 = *reinterpret_cast<const half8*>(baseB[2] + kn);
    }
    half8 af[4], bf[5];
    #pragma unroll
    for (int mi = 0; mi < 4; ++mi)
      af[mi] = *reinterpret_cast<const half8*>(&Abuf[cur][roA + mi * 640]);
    #pragma unroll
    for (int ni = 0; ni < 5; ++ni)
      bf[ni] = *reinterpret_cast<const half8*>(&Bbuf[cur][roB + ni * 640]);
    #pragma unroll
    for (int mi = 0; mi < 4; ++mi)
      #pragma unroll
      for (int ni = 0; ni < 5; ++ni)
        acc[mi][ni] = __builtin_amdgcn_mfma_f32_16x16x32_f16(af[mi], bf[ni], acc[mi][ni], 0, 0, 0);
    if (more) {
      *reinterpret_cast<half8*>(&Abuf[cur ^ 1][wo]) = rA0;
      *reinterpret_cast<half8*>(&Abuf[cur ^ 1][wo + 2560]) = rA1;
      *reinterpret_cast<half8*>(&Bbuf[cur ^ 1][wo]) = rB0;
      *reinterpret_cast<half8*>(&Bbuf[cur ^ 1][wo + 2560]) = rB1;
      if (t < 128) *reinterpret_cast<half8*>(&Bbuf[cur ^ 1][wo + 5120]) = rB2;
    }
    __syncthreads();
  }

  #pragma unroll
  for (int ni = 0; ni < 5; ++ni) {
    int col = c0 + wn * 80 + ni * 16 + lo;
    float bv = ob[col];
    #pragma unroll
    for (int mi = 0; mi < 4; ++mi)
      #pragma unroll
      for (int rr = 0; rr < 4; ++rr) {
        int row = r0 + wm * 64 + mi * 16 + hi * 4 + rr;
        lnb[(size_t)row * 800 + col] = (_Float16)(acc[mi][ni][rr] + bv);
      }
  }
}

// ---------------- a2 + global max row/col sums ----------------
__global__ __launch_bounds__(64) void k_a2(
    const float* __restrict__ ql, const float* __restrict__ kl,
    float* __restrict__ a2, float* __restrict__ scal) {
  __shared__ float sp[64 * 65];
  const int bh = blockIdx.x, t = threadIdx.x;
  const float* qr = ql + ((size_t)bh * 64 + t) * 64;
  const float* kb = kl + (size_t)bh * 4096;
  float mx = -1e30f;
  for (int c = 0; c < 64; ++c) {
    float acc = 0.f;
    #pragma unroll 8
    for (int dd = 0; dd < 64; ++dd) acc = fmaf(qr[dd], kb[c * 64 + dd], acc);
    sp[t * 65 + c] = acc;
    mx = fmaxf(mx, acc);
  }
  float sum = 0.f;
  for (int c = 0; c < 64; ++c) {
    float e = expf(sp[t * 65 + c] - mx);
    sp[t * 65 + c] = e;
    sum += e;
  }
  float inv = 1.f / sum;
  float rs = 0.f;
  for (int c = 0; c < 64; ++c) {
    float p = sp[t * 65 + c] * inv;
    sp[t * 65 + c] = p;
    a2[(size_t)bh * 4096 + t * 64 + c] = p;
    rs += p;
  }
  atomicMax(reinterpret_cast<int*>(scal), __float_as_int(rs));
  __syncthreads();
  float cs = 0.f;
  for (int r = 0; r < 64; ++r) cs += sp[r * 65 + t];
  atomicMax(reinterpret_cast<int*>(scal) + 1, __float_as_int(cs));
}

// ---------------- fused a3 softmax + a3@v ----------------
__global__ __launch_bounds__(256) void k_a3v(
    const float* __restrict__ ql, const _Float16* __restrict__ kT,
    const _Float16* __restrict__ vx, float* __restrict__ a3v) {
  __shared__ float sq[64];
  __shared__ float sP[4096];
  __shared__ float red[4];
  __shared__ float red2[4][64];
  const int t = threadIdx.x;
  const int m = blockIdx.x, bh = blockIdx.y;
  if (t < 64) sq[t] = ql[((size_t)bh * 64 + m) * 64 + t];
  __syncthreads();
  const _Float16* kb = kT + (size_t)bh * 262144;
  float sc[16];
  #pragma unroll
  for (int i = 0; i < 16; ++i) sc[i] = 0.f;
  for (int dd = 0; dd < 64; ++dd) {
    float qv = sq[dd];
    const half8* kr = reinterpret_cast<const half8*>(kb + (size_t)dd * 4096 + t * 16);
    half8 k0 = kr[0], k1 = kr[1];
    #pragma unroll
    for (int i = 0; i < 8; ++i) sc[i] = fmaf(qv, (float)k0[i], sc[i]);
    #pragma unroll
    for (int i = 0; i < 8; ++i) sc[8 + i] = fmaf(qv, (float)k1[i], sc[8 + i]);
  }
  float mx = sc[0];
  #pragma unroll
  for (int i = 1; i < 16; ++i) mx = fmaxf(mx, sc[i]);
  #pragma unroll
  for (int o = 32; o; o >>= 1) mx = fmaxf(mx, __shfl_xor(mx, o));
  if ((t & 63) == 0) red[t >> 6] = mx;
  __syncthreads();
  mx = fmaxf(fmaxf(red[0], red[1]), fmaxf(red[2], red[3]));
  __syncthreads();
  float sum = 0.f;
  #pragma unroll
  for (int i = 0; i < 16; ++i) {
    sc[i] = expf(sc[i] - mx);
    sum += sc[i];
  }
  #pragma unroll
  for (int o = 32; o; o >>= 1) sum += __shfl_xor(sum, o);
  if ((t & 63) == 0) red[t >> 6] = sum;
  __syncthreads();
  sum = red[0] + red[1] + red[2] + red[3];
  float inv = 1.f / sum;
  #pragma unroll
  for (int i = 0; i < 16; ++i) sP[t * 16 + i] = sc[i] * inv;
  __syncthreads();
  const int seg = t >> 6, l = t & 63;
  const int nl = l >> 3, dblk = (l & 7) * 8;
  const _Float16* vb = vx + (size_t)bh * 262144;
  float acc8[8] = {};
  for (int it = 0; it < 128; ++it) {
    int n8 = seg * 1024 + it * 8;
    half8 vv = *reinterpret_cast<const half8*>(&vb[(size_t)(n8 + nl) * 64 + dblk]);
    float pc = sP[n8 + nl];
    #pragma unroll
    for (int u = 0; u < 8; ++u) acc8[u] = fmaf(pc, (float)vv[u], acc8[u]);
  }
  #pragma unroll
  for (int off = 8; off <= 32; off <<= 1)
    #pragma unroll
    for (int u = 0; u < 8; ++u) acc8[u] += __shfl_xor(acc8[u], off);
  if (nl == 0) {
    #pragma unroll
    for (int u = 0; u < 8; ++u) red2[seg][dblk + u] = acc8[u];
  }
  __syncthreads();
  if (seg == 0)
    a3v[((size_t)bh * 64 + m) * 64 + l] = red2[0][l] + red2[1][l] + red2[2][l] + red2[3][l];
}

// ---------------- Moore-Penrose pinv + fused w2t ----------------
__global__ __launch_bounds__(256) void k_pinv(
    const float* __restrict__ a2g, const float* __restrict__ scal,
    const float* __restrict__ a3vg, _Float16* __restrict__ w2t) {
  __shared__ float z[64 * 68];
  __shared__ float az[64 * 68];
  __shared__ float tb[64 * 68];
  const int bh = blockIdx.x, t = threadIdx.x;
  const int r0 = (t >> 4) << 2, c0 = (t & 15) << 2;
  const float* ag = a2g + (size_t)bh * 4096;
  const float denom = 1.f / (scal[0] * scal[1]);
  #pragma unroll
  for (int i = 0; i < 4; ++i)
    #pragma unroll
    for (int j = 0; j < 4; ++j)
      z[(r0 + i) * 68 + c0 + j] = ag[(c0 + j) * 64 + r0 + i] * denom;
  __syncthreads();
  float reg[4][4], val[4][4];
  for (int it = 0; it < 6; ++it) {
    mm16v<64, 68>(ag, z, r0, c0, reg);
    #pragma unroll
    for (int i = 0; i < 4; ++i)
      #pragma unroll
      for (int j = 0; j < 4; ++j) az[(r0 + i) * 68 + c0 + j] = reg[i][j];
    __syncthreads();
    mm16v<68, 68>(az, az, r0, c0, reg);
    #pragma unroll
    for (int i = 0; i < 4; ++i)
      #pragma unroll
      for (int j = 0; j < 4; ++j)
        tb[(r0 + i) * 68 + c0 + j] = 7.f * az[(r0 + i) * 68 + c0 + j] - reg[i][j];
    __syncthreads();
    mm16v<68, 68>(az, tb, r0, c0, reg);
    #pragma unroll
    for (int i = 0; i < 4; ++i)
      #pragma unroll
      for (int j = 0; j < 4; ++j)
        val[i][j] = 15.f * az[(r0 + i) * 68 + c0 + j] - reg[i][j];
    __syncthreads();
    #pragma unroll
    for (int i = 0; i < 4; ++i)
      #pragma unroll
      for (int j = 0; j < 4; ++j) tb[(r0 + i) * 68 + c0 + j] = val[i][j];
    __syncthreads();
    mm16v<68, 68>(z, tb, r0, c0, reg);
    #pragma unroll
    for (int i = 0; i < 4; ++i)
      #pragma unroll
      for (int j = 0; j < 4; ++j)
        val[i][j] = 0.25f * (13.f * z[(r0 + i) * 68 + c0 + j] - reg[i][j]);
    __syncthreads();
    #pragma unroll
    for (int i = 0; i < 4; ++i)
      #pragma unroll
      for (int j = 0; j < 4; ++j) z[(r0 + i) * 68 + c0 + j] = val[i][j];
    __syncthreads();
  }
  mm16v<68, 64>(z, a3vg + (size_t)bh * 4096, r0, c0, reg);
  #pragma unroll
  for (int i = 0; i < 4; ++i)
    #pragma unroll
    for (int j = 0; j < 4; ++j)
      w2t[(size_t)bh * 4096 + (c0 + j) * 64 + (r0 + i)] = (_Float16)reg[i][j];
}

// ------- fused MFMA combine ------------
__global__ __launch_bounds__(256) void k_combine_m(
    const _Float16* __restrict__ qx, const _Float16* __restrict__ klh,
    const _Float16* __restrict__ w2t, const _Float16* __restrict__ vx,
    const float* __restrict__ rw, _Float16* __restrict__ att) {
  __shared__ _Float16 sP[64 * 72];
  __shared__ _Float16 sVT[64 * 104];
  __shared__ _Float16 sT[64 * 104];
  __shared__ float sR[33];
  const int t = threadIdx.x, w = t >> 6, lo = t & 15, hi = (t >> 4) & 3;
  const int n0 = blockIdx.x * 64;
  const int h = blockIdx.y, b = blockIdx.z, bh = b * 8 + h;
  if (t < 33) sR[t] = rw[h * 33 + t];
  __syncthreads();
  const _Float16* vb = vx + (size_t)bh * 262144;
  #pragma unroll
  for (int u = 0; u < 24; ++u) {
    int e = t + u * 256;
    int r = e >> 6, d = e & 63;
    int nn = n0 - 16 + r;
    sVT[d * 104 + r] = ((unsigned)nn < 4096u) ? vb[(size_t)nn * 64 + d] : (_Float16)0.f;
  }
  #pragma unroll
  for (int u = 0; u < 24; ++u) {
    int e = t + u * 256;
    int r = e % 96, i = e / 96;
    int j = r - i;
    sT[i * 104 + r] = (j >= 0 && j < 33) ? (_Float16)sR[j] : (_Float16)0.f;
  }
  f32x4 sa[4] = {};
  const _Float16* qp = qx + ((size_t)bh * 4096 + n0 + w * 16 + lo) * 64 + 8 * hi;
  const _Float16* klp = klh + (size_t)bh * 4096;
  #pragma unroll
  for (int c = 0; c < 2; ++c) {
    half8 a = *reinterpret_cast<const half8*>(qp + 32 * c);
    #pragma unroll
    for (int ct = 0; ct < 4; ++ct) {
      half8 bf = *reinterpret_cast<const half8*>(klp + (size_t)(ct * 16 + lo) * 64 + 8 * hi + 32 * c);
      sa[ct] = __builtin_amdgcn_mfma_f32_16x16x32_f16(a, bf, sa[ct], 0, 0, 0);
    }
  }
  #pragma unroll
  for (int r = 0; r < 4; ++r) {
    float mx = fmaxf(fmaxf(sa[0][r], sa[1][r]), fmaxf(sa[2][r], sa[3][r]));
    #pragma unroll
    for (int o = 8; o; o >>= 1) mx = fmaxf(mx, __shfl_xor(mx, o));
    float e0 = expf(sa[0][r] - mx), e1 = expf(sa[1][r] - mx);
    float e2 = expf(sa[2][r] - mx), e3 = expf(sa[3][r] - mx);
    float sm = e0 + e1 + e2 + e3;
    #pragma unroll
    for (int o = 8; o; o >>= 1) sm += __shfl_xor(sm, o);
    float inv = 1.f / sm;
    int row = w * 16 + hi * 4 + r;
    sP[row * 72 + lo] = (_Float16)(e0 * inv);
    sP[row * 72 + 16 + lo] = (_Float16)(e1 * inv);
    sP[row * 72 + 32 + lo] = (_Float16)(e2 * inv);
    sP[row * 72 + 48 + lo] = (_Float16)(e3 * inv);
  }
  __syncthreads();
  f32x4 ao[4] = {};
  const _Float16* w2p = w2t + (size_t)bh * 4096;
  #pragma unroll
  for (int c = 0; c < 2; ++c) {
    half8 a = *reinterpret_cast<const half8*>(&sP[(w * 16 + lo) * 72 + 8 * hi + 32 * c]);
    #pragma unroll
    for (int ct = 0; ct < 4; ++ct) {
      half8 bf = *reinterpret_cast<const half8*>(w2p + (size_t)(ct * 16 + lo) * 64 + 8 * hi + 32 * c);
      ao[ct] = __builtin_amdgcn_mfma_f32_16x16x32_f16(a, bf, ao[ct], 0, 0, 0);
    }
  }
  #pragma unroll
  for (int c = 0; c < 3; ++c) {
    half8 a = *reinterpret_cast<const half8*>(&sT[(w * 16 + lo) * 104 + 8 * hi + 32 * c]);
    #pragma unroll
    for (int ct = 0; ct < 4; ++ct) {
      half8 bf = *reinterpret_cast<const half8*>(&sVT[(ct * 16 + lo) * 104 + 8 * hi + 32 * c]);
      ao[ct] = __builtin_amdgcn_mfma_f32_16x16x32_f16(a, bf, ao[ct], 0, 0, 0);
    }
  }
  _Float16* ab = att + ((size_t)b * 4096) * 512 + (size_t)h * 64;
  #pragma unroll
  for (int ct = 0; ct < 4; ++ct)
    #pragma unroll
    for (int r = 0; r < 4; ++r) {
      int n = n0 + w * 16 + hi * 4 + r;
      ab[(size_t)n * 512 + ct * 16 + lo] = (_Float16)ao[ct][r];
    }
}

// ---------------- fused LayerNorm + head MFMA ----------------
__global__ __launch_bounds__(256) void k_lnhead(
    const _Float16* __restrict__ ln, const _Float16* __restrict__ hwh,
    const float* __restrict__ g, const float* __restrict__ bb,
    const float* __restrict__ hb, float* __restrict__ out) {
  const int t = threadIdx.x, w = t >> 6, lo = t & 15, hi = (t >> 4) & 3;
  const int row0 = blockIdx.x * 64 + w * 16;
  const _Float16* ap = ln + (size_t)(row0 + lo) * 800 + 8 * hi;
  float s1 = 0.f, s2 = 0.f;
  #pragma unroll 5
  for (int k = 0; k < 800; k += 32) {
    half8 a = *reinterpret_cast<const half8*>(ap + k);
    #pragma unroll
    for (int u = 0; u < 8; ++u) {
      float x = (float)a[u];
      s1 += x;
      s2 = fmaf(x, x, s2);
    }
  }
  s1 += __shfl_xor(s1, 16); s1 += __shfl_xor(s1, 32);
  s2 += __shfl_xor(s2, 16); s2 += __shfl_xor(s2, 32);
  float mean = s1 * (1.f / 800.f);
  float var = s2 * (1.f / 800.f) - mean * mean;
  float rstd = rsqrtf(var + LN_EPS_C);
  const _Float16* bp = hwh + (size_t)lo * 800 + 8 * hi;
  f32x4 acc = {};
  #pragma unroll 5
  for (int k = 0; k < 800; k += 32) {
    half8 a = *reinterpret_cast<const half8*>(ap + k);
    half8 an;
    #pragma unroll
    for (int u = 0; u < 8; ++u) {
      int kk = k + 8 * hi + u;
      float x = ((float)a[u] - mean) * rstd * g[kk] + bb[kk];
      an[u] = (_Float16)x;
    }
    half8 b = *reinterpret_cast<const half8*>(bp + k);
    acc = __builtin_amdgcn_mfma_f32_16x16x32_f16(an, b, acc, 0, 0, 0);
  }
  float bv = hb[lo];
  #pragma unroll
  for (int r = 0; r < 4; ++r) {
    int row = row0 + hi * 4 + r;
    out[(size_t)row * 16 + lo] = 1.f / (1.f + expf(-(acc[r] + bv)));
  }
}

// ---------------- launcher ----------------
extern "C" void kernel_launch(void* const* d_in, const int* in_sizes, int n_in,
                              void* d_out, int out_size, void* d_ws, size_t ws_size,
                              hipStream_t stream) {
  (void)in_sizes; (void)n_in; (void)out_size; (void)ws_size;
  const float* x     = (const float*)d_in[0];
  const float* w0    = (const float*)d_in[1];
  const float* b0    = (const float*)d_in[2];
  const float* g0    = (const float*)d_in[3];
  const float* be0   = (const float*)d_in[4];
  const float* mu0   = (const float*)d_in[5];
  const float* var0  = (const float*)d_in[6];
  const float* w1    = (const float*)d_in[7];
  const float* b1    = (const float*)d_in[8];
  const float* g1    = (const float*)d_in[9];
  const float* be1   = (const float*)d_in[10];
  const float* mu1   = (const float*)d_in[11];
  const float* var1  = (const float*)d_in[12];
  const float* w2c   = (const float*)d_in[13];
  const float* b2    = (const float*)d_in[14];
  const float* g2    = (const float*)d_in[15];
  const float* be2   = (const float*)d_in[16];
  const float* mu2   = (const float*)d_in[17];
  const float* var2  = (const float*)d_in[18];
  const float* w3    = (const float*)d_in[19];
  const float* b3    = (const float*)d_in[20];
  const float* g3    = (const float*)d_in[21];
  const float* be3   = (const float*)d_in[22];
  const float* mu3   = (const float*)d_in[23];
  const float* var3  = (const float*)d_in[24];
  const float* qkvw  = (const float*)d_in[25];
  const float* outw  = (const float*)d_in[26];
  const float* outbv = (const float*)d_in[27];
  const float* resw  = (const float*)d_in[28];
  const float* lng   = (const float*)d_in[29];
  const float* lnbv  = (const float*)d_in[30];
  const float* headw = (const float*)d_in[31];
  const float* headb = (const float*)d_in[32];

  char* wsb = (char*)d_ws;
  _Float16* h0   = (_Float16*)(wsb + B_H0);
  _Float16* h1   = (_Float16*)(wsb + B_H1);
  _Float16* h2   = (_Float16*)(wsb + B_H2);
  _Float16* qb   = (_Float16*)(wsb + B_Q);
  _Float16* vb   = (_Float16*)(wsb + B_V);
  _Float16* kT   = (_Float16*)(wsb + B_KT);
  _Float16* tok  = (_Float16*)(wsb + B_TOK);
  _Float16* attb = (_Float16*)(wsb + B_ATT);
  _Float16* wp1  = (_Float16*)(wsb + B_WP1);
  _Float16* wp2  = (_Float16*)(wsb + B_WP2);
  _Float16* wp3  = (_Float16*)(wsb + B_WP3);
  _Float16* qkvT = (_Float16*)(wsb + B_QKVT);
  _Float16* owT  = (_Float16*)(wsb + B_OWT);
  _Float16* klh  = (_Float16*)(wsb + B_KLH);
  _Float16* w2t  = (_Float16*)(wsb + B_W2T);
  _Float16* hwh  = (_Float16*)(wsb + B_HWH);
  _Float16* lnb16 = (_Float16*)(wsb + B_LNB);
  float* ql   = (float*)(wsb + B_QL);
  float* kl   = (float*)(wsb + B_KL);
  float* a2   = (float*)(wsb + B_A2);
  float* a3v  = (float*)(wsb + B_A3V);
  float* scal = (float*)(wsb + B_SCAL);

  k_pack_all<<<dim3(20691), 256, 0, stream>>>(
      w1, w2c, w3, qkvw, outw, headw, wp1, wp2, wp3, qkvT, owT, hwh, scal);

  for (int img = 0; img < 4; ++img) {
    k_conv0<<<dim3(256, 4), 256, 0, stream>>>(
        x + (size_t)img * 65536, w0, b0, g0, be0, mu0, var0, h0);
    k_convs<64><<<dim3(512), 256, 0, stream>>>(
        h0, wp1, b1, g1, be1, mu1, var1, h1, 128, 1);
    k_convs<128><<<dim3(1024), 256, 0, stream>>>(
        h1, wp2, b2, g2, be2, mu2, var2, h2 + (size_t)img * 16777216, 256, 2);
  }
  k_c3<<<dim3(640), 256, 0, stream>>>(h2, wp3, b3, g3, be3, mu3, var3, tok);
  k_qkv_s<<<dim3(1536), 256, 0, stream>>>(tok, qkvT, qb, kT, vb, ql, kl, klh);
  k_a2<<<dim3(32), 64, 0, stream>>>(ql, kl, a2, scal);
  k_a3v<<<dim3(64, 32), 256, 0, stream>>>(ql, kT, vb, a3v);
  k_pinv<<<dim3(32), 256, 0, stream>>>(a2, scal, a3v, w2t);
  k_combine_m<<<dim3(64, 8, 4), 256, 0, stream>>>(qb, klh, w2t, vb, resw, attb);
  k_op_s<<<dim3(640), 256, 0, stream>>>(attb, owT, outbv, lnb16);
  k_lnhead<<<dim3(256), 256, 0, stream>>>(lnb16, hwh, lng, lnbv, headb, (float*)d_out);
}

// Round 14
// 940.258 us; speedup vs baseline: 1.0151x; 1.0151x over previous
//
#include <hip/hip_runtime.h>

#define DI __device__ __forceinline__

constexpr float BN_EPS_C = 1e-5f;
constexpr float LN_EPS_C = 1e-5f;

typedef _Float16 half8 __attribute__((ext_vector_type(8)));
typedef float f32x4 __attribute__((ext_vector_type(4)));

// ---------------- workspace layout (BYTE offsets), peak ~199.34 MB ----------------
constexpr size_t B_H0   = 0;
constexpr size_t B_H1   = 8388608;
constexpr size_t B_H2   = 25165824;      // f16 [4][256][256][256] = 134,217,728
constexpr size_t B_Q    = 25165824;
constexpr size_t B_V    = 58720256;
constexpr size_t B_KT   = 75497472;
constexpr size_t B_ATT  = 92274688;
constexpr size_t B_LNB  = 25165824;
constexpr size_t B_TOK  = 159383552;
constexpr size_t B_WP1  = 185597952;
constexpr size_t B_WP2  = 185745408;
constexpr size_t B_WP3  = 186335232;
constexpr size_t B_QKVT = 192888832;
constexpr size_t B_OWT  = 195346432;
constexpr size_t B_QL   = 196165632;
constexpr size_t B_KL   = 196689920;
constexpr size_t B_KLH  = 197214208;
constexpr size_t B_A2   = 197476352;
constexpr size_t B_W2T  = 198524928;
constexpr size_t B_A3V  = 198787072;
constexpr size_t B_SCAL = 199311360;
constexpr size_t B_HWH  = 199311424;

// ---------------- helpers ----------------
DI void gl_lds16(const _Float16* g, _Float16* l) {
  __builtin_amdgcn_global_load_lds(
      (const __attribute__((address_space(1))) void*)g,
      (__attribute__((address_space(3))) void*)l, 16, 0, 0);
}

template <int LP, int RP>
DI void mm16v(const float* L, const float* R, int r0, int c0, float reg[4][4]) {
  #pragma unroll
  for (int i = 0; i < 4; ++i)
    #pragma unroll
    for (int j = 0; j < 4; ++j) reg[i][j] = 0.f;
  #pragma unroll 4
  for (int dd = 0; dd < 64; dd += 4) {
    f32x4 l[4], rv[4];
    #pragma unroll
    for (int i = 0; i < 4; ++i)
      l[i] = *reinterpret_cast<const f32x4*>(&L[(size_t)(r0 + i) * LP + dd]);
    #pragma unroll
    for (int u = 0; u < 4; ++u)
      rv[u] = *reinterpret_cast<const f32x4*>(&R[(size_t)(dd + u) * RP + c0]);
    #pragma unroll
    for (int i = 0; i < 4; ++i)
      #pragma unroll
      for (int u = 0; u < 4; ++u)
        #pragma unroll
        for (int j = 0; j < 4; ++j)
          reg[i][j] = fmaf(l[i][u], rv[u][j], reg[i][j]);
  }
}

// ---------------- mega-pack ----------------
__global__ void k_pack_all(
    const float* __restrict__ w1, const float* __restrict__ w2c, const float* __restrict__ w3,
    const float* __restrict__ qkvw, const float* __restrict__ outw, const float* __restrict__ headw,
    _Float16* __restrict__ wp1, _Float16* __restrict__ wp2, _Float16* __restrict__ wp3,
    _Float16* __restrict__ qkvT, _Float16* __restrict__ owT, _Float16* __restrict__ hwh,
    float* __restrict__ scal) {
  size_t i = (size_t)blockIdx.x * 256 + threadIdx.x;
  if (i < 73728) {
    int q = i % 9, ci = (i / 9) % 64, co = i / (9 * 64);
    wp1[((size_t)co * 9 + q) * 64 + ci] = (_Float16)w1[i];
  } else if (i < 368640) {
    size_t j = i - 73728;
    int q = j % 9, ci = (j / 9) % 128, co = j / (9 * 128);
    wp2[((size_t)co * 9 + q) * 128 + ci] = (_Float16)w2c[j];
  } else if (i < 3645440) {
    size_t j = i - 368640;
    int q = j % 16, ci = (j / 16) % 256, co = j / (16 * 256);
    wp3[((size_t)co * 16 + q) * 256 + ci] = (_Float16)w3[j];
  } else if (i < 4874240) {
    size_t j = i - 3645440;
    int n = j % 1536, k = j / 1536;
    qkvT[(size_t)n * 800 + k] = (_Float16)qkvw[j];
  } else if (i < 5283840) {
    size_t j = i - 4874240;
    int n = j % 800, k = j / 800;
    owT[(size_t)n * 512 + k] = (_Float16)outw[j];
  } else if (i < 5296640) {
    size_t j = i - 5283840;
    int n = j % 16, k = j / 16;
    hwh[(size_t)n * 800 + k] = (_Float16)headw[j];
  } else if (i < 5296642) {
    scal[i - 5296640] = 0.f;
  }
}

// ---------------- conv0 ----------------
__global__ __launch_bounds__(256) void k_conv0(
    const float* __restrict__ xb, const float* __restrict__ w0, const float* __restrict__ b0,
    const float* __restrict__ g0, const float* __restrict__ be0, const float* __restrict__ mu0,
    const float* __restrict__ var0, _Float16* __restrict__ h0) {
  const int t = threadIdx.x, co = t & 63, xg = t >> 6;
  const int y = blockIdx.x;
  const int x0 = blockIdx.y * 64 + xg * 16;
  float wreg[9];
  #pragma unroll
  for (int q = 0; q < 9; ++q) wreg[q] = w0[co * 9 + q];
  float s = g0[co] * rsqrtf(var0[co] + BN_EPS_C);
  float sh = fmaf(b0[co] - mu0[co], s, be0[co]);
  #pragma unroll 4
  for (int xl = 0; xl < 16; ++xl) {
    int xx = x0 + xl;
    float acc = 0.f;
    #pragma unroll
    for (int dy = 0; dy < 3; ++dy) {
      int yy = y + dy - 1;
      if ((unsigned)yy >= 256u) continue;
      #pragma unroll
      for (int dx = 0; dx < 3; ++dx) {
        int xi = xx + dx - 1;
        if ((unsigned)xi >= 256u) continue;
        acc = fmaf(wreg[dy * 3 + dx], xb[yy * 256 + xi], acc);
      }
    }
    float v = fmaxf(fmaf(acc, s, sh), 0.f);
    h0[((size_t)y * 256 + xx) * 64 + co] = (_Float16)v;
  }
}

// ------- staged implicit-im2col 3x3 conv GEMM: tile 128x128 (r11 single-deep) -----------
template <int CI>
__global__ __launch_bounds__(256) void k_convs(
    const _Float16* __restrict__ in, const _Float16* __restrict__ wp,
    const float* __restrict__ bias, const float* __restrict__ g, const float* __restrict__ be,
    const float* __restrict__ mu, const float* __restrict__ var,
    _Float16* __restrict__ out, int CO, int NCT) {
  __shared__ _Float16 Ab[2][128 * 40];
  __shared__ _Float16 Bb[2][128 * 40];
  constexpr int CPQ = CI / 32;
  constexpr int NCK = 9 * CPQ;
  const int t = threadIdx.x;
  const int bid = blockIdx.x;
  const int xcd = bid & 7, slot = bid >> 3;
  const int pj = slot / NCT, cc = slot % NCT;
  const int p = pj * 8 + xcd;
  const int r0 = p * 128, c0 = cc * 128;

  const int ma = t >> 2, kga = t & 3;
  int ry[2], rx[2];
  #pragma unroll
  for (int s = 0; s < 2; ++s) {
    int r = r0 + ma + s * 64;
    ry[s] = r >> 8;
    rx[s] = r & 255;
  }
  const _Float16* baseB[2];
  #pragma unroll
  for (int s = 0; s < 2; ++s)
    baseB[s] = wp + (size_t)(c0 + ma + s * 64) * 9 * CI + kga * 8;
  const int wo = ma * 40 + kga * 8;

  auto loadA = [&](int s, int ck) -> half8 {
    int q = ck / CPQ, coff = (ck % CPQ) * 32;
    int yy = ry[s] + q / 3 - 1;
    int xx = rx[s] + q % 3 - 1;
    half8 a = {};
    if ((unsigned)yy < 256u && (unsigned)xx < 256u)
      a = *reinterpret_cast<const half8*>(in + ((size_t)yy * 256 + xx) * CI + coff + kga * 8);
    return a;
  };

  {
    half8 a0 = loadA(0, 0), a1 = loadA(1, 0);
    half8 b0v = *reinterpret_cast<const half8*>(baseB[0]);
    half8 b1v = *reinterpret_cast<const half8*>(baseB[1]);
    *reinterpret_cast<half8*>(&Ab[0][wo]) = a0;
    *reinterpret_cast<half8*>(&Ab[0][wo + 2560]) = a1;
    *reinterpret_cast<half8*>(&Bb[0][wo]) = b0v;
    *reinterpret_cast<half8*>(&Bb[0][wo + 2560]) = b1v;
  }
  __syncthreads();

  const int w = t >> 6, lo = t & 15, hi = (t >> 4) & 3;
  const int wm = w >> 1, wn = w & 1;
  const int roA = (wm * 64 + lo) * 40 + 8 * hi;
  const int roB = (wn * 64 + lo) * 40 + 8 * hi;
  f32x4 acc[4][4] = {};

  for (int ck = 0; ck < NCK; ++ck) {
    const int cur = ck & 1;
    const bool more = (ck + 1 < NCK);
    half8 rA0, rA1, rB0, rB1;
    if (more) {
      rA0 = loadA(0, ck + 1);
      rA1 = loadA(1, ck + 1);
      rB0 = *reinterpret_cast<const half8*>(baseB[0] + (ck + 1) * 32);
      rB1 = *reinterpret_cast<const half8*>(baseB[1] + (ck + 1) * 32);
    }
    half8 af[4], bf[4];
    #pragma unroll
    for (int mi = 0; mi < 4; ++mi)
      af[mi] = *reinterpret_cast<const half8*>(&Ab[cur][roA + mi * 640]);
    #pragma unroll
    for (int ni = 0; ni < 4; ++ni)
      bf[ni] = *reinterpret_cast<const half8*>(&Bb[cur][roB + ni * 640]);
    #pragma unroll
    for (int mi = 0; mi < 4; ++mi)
      #pragma unroll
      for (int ni = 0; ni < 4; ++ni)
        acc[mi][ni] = __builtin_amdgcn_mfma_f32_16x16x32_f16(af[mi], bf[ni], acc[mi][ni], 0, 0, 0);
    if (more) {
      *reinterpret_cast<half8*>(&Ab[cur ^ 1][wo]) = rA0;
      *reinterpret_cast<half8*>(&Ab[cur ^ 1][wo + 2560]) = rA1;
      *reinterpret_cast<half8*>(&Bb[cur ^ 1][wo]) = rB0;
      *reinterpret_cast<half8*>(&Bb[cur ^ 1][wo + 2560]) = rB1;
    }
    __syncthreads();
  }

  #pragma unroll
  for (int ni = 0; ni < 4; ++ni) {
    int co = c0 + wn * 64 + ni * 16 + lo;
    float s = g[co] * rsqrtf(var[co] + BN_EPS_C);
    float sh = fmaf(bias[co] - mu[co], s, be[co]);
    #pragma unroll
    for (int mi = 0; mi < 4; ++mi)
      #pragma unroll
      for (int rr = 0; rr < 4; ++rr) {
        int row = r0 + wm * 64 + mi * 16 + hi * 4 + rr;
        float v = fmaxf(fmaf(acc[mi][ni][rr], s, sh), 0.f);
        out[(size_t)row * CO + co] = (_Float16)v;
      }
  }
}

// ------- conv3: staged GEMM 128x160 via global_load_lds (linear LDS + XOR k-slot swizzle) ---
// LDS pitch 32 halfs (lane-linear dest). Source-side involution: lane l loads k-slot
// (l&3)^((l>>3)&3); read-side: slot = hi ^ ((lo>>1)&3). Residual bank aliasing = 2-way (free).
__global__ __launch_bounds__(256) void k_c3(
    const _Float16* __restrict__ h2, const _Float16* __restrict__ wp3,
    const float* __restrict__ b3, const float* __restrict__ g3, const float* __restrict__ be3,
    const float* __restrict__ mu3, const float* __restrict__ var3,
    _Float16* __restrict__ tok) {
  __shared__ _Float16 Abuf[2][128 * 32];
  __shared__ _Float16 Bbuf[2][160 * 32];
  const int t = threadIdx.x;
  const int bid = blockIdx.x;
  const int xcd = bid & 7, slot = bid >> 3;
  const int pj = slot / 5, cc = slot % 5;
  const int p = pj * 8 + xcd;
  const int r0 = p * 128, c0 = cc * 160;
  const int img = r0 >> 12;
  const _Float16* h2i = h2 + (size_t)img * 16777216;

  const int w = t >> 6, l = t & 63;
  const int kslot = (l & 3) ^ ((l >> 3) & 3);
  // A global sources: issue s covers LDS rows 16w+(l>>2)+64s
  const _Float16* gA[2];
  #pragma unroll
  for (int s = 0; s < 2; ++s) {
    int mar = 16 * w + (l >> 2) + 64 * s;
    int r = r0 + mar;
    int py = (r & 4095) >> 6, px = r & 63;
    gA[s] = h2i + ((size_t)py * 1024 + px * 4) * 256 + kslot * 8;
  }
  // B global sources: s=0,1 all waves; s=2 only waves 0,1 (rows 128..159)
  const _Float16* gB[3];
  #pragma unroll
  for (int s = 0; s < 3; ++s) {
    int rb = 16 * w + (l >> 2) + 64 * s;
    if (rb > 159) rb = 159;                       // never issued for invalid waves
    gB[s] = wp3 + (size_t)(c0 + rb) * 4096 + kslot * 8;
  }

  const int lo = t & 15, hi = (t >> 4) & 3;
  const int wm = w >> 1, wn = w & 1;
  const int sl = hi ^ ((lo >> 1) & 3);
  const int roA = (wm * 64 + lo) * 32 + sl * 8;   // + mi*512
  const int roB = (wn * 80 + lo) * 32 + sl * 8;   // + ni*512

  f32x4 acc[4][5] = {};

  auto STAGE = [&](int buf, int ck) {
    const int kn = ck << 5;
    const int q = kn >> 8;
    const size_t aoff = (size_t)(q >> 2) * 65536 + (size_t)(q & 3) * 256 + (kn & 255);
    _Float16* Ad = &Abuf[buf][512 * w];
    _Float16* Bd = &Bbuf[buf][512 * w];
    gl_lds16(gA[0] + aoff, Ad);
    gl_lds16(gA[1] + aoff, Ad + 2048);
    gl_lds16(gB[0] + kn, Bd);
    gl_lds16(gB[1] + kn, Bd + 2048);
    if (w < 2) gl_lds16(gB[2] + kn, Bd + 4096);
  };

  STAGE(0, 0);
  __syncthreads();

  for (int ck = 0; ck < 128; ++ck) {
    const int cur = ck & 1;
    if (ck + 1 < 128) STAGE(cur ^ 1, ck + 1);
    half8 af[4], bf[5];
    #pragma unroll
    for (int mi = 0; mi < 4; ++mi)
      af[mi] = *reinterpret_cast<const half8*>(&Abuf[cur][roA + mi * 512]);
    #pragma unroll
    for (int ni = 0; ni < 5; ++ni)
      bf[ni] = *reinterpret_cast<const half8*>(&Bbuf[cur][roB + ni * 512]);
    #pragma unroll
    for (int mi = 0; mi < 4; ++mi)
      #pragma unroll
      for (int ni = 0; ni < 5; ++ni)
        acc[mi][ni] = __builtin_amdgcn_mfma_f32_16x16x32_f16(af[mi], bf[ni], acc[mi][ni], 0, 0, 0);
    __syncthreads();
  }

  #pragma unroll
  for (int ni = 0; ni < 5; ++ni) {
    int col = c0 + wn * 80 + ni * 16 + lo;
    float s = g3[col] * rsqrtf(var3[col] + BN_EPS_C);
    float sh = fmaf(b3[col] - mu3[col], s, be3[col]);
    #pragma unroll
    for (int mi = 0; mi < 4; ++mi)
      #pragma unroll
      for (int rr = 0; rr < 4; ++rr) {
        int row = r0 + wm * 64 + mi * 16 + hi * 4 + rr;
        float v = fmaxf(fmaf(acc[mi][ni][rr], s, sh), 0.f);
        tok[(size_t)row * 800 + col] = (_Float16)v;
      }
  }
}

// ---------------- qkv staged GEMM + fused landmarks; kT via LDS transpose -----------------
__global__ __launch_bounds__(256) void k_qkv_s(
    const _Float16* __restrict__ tok, const _Float16* __restrict__ qkvT,
    _Float16* __restrict__ qx, _Float16* __restrict__ kTg, _Float16* __restrict__ vx,
    float* __restrict__ ql, float* __restrict__ kl, _Float16* __restrict__ klh) {
  __shared__ _Float16 SH[20480];
  _Float16* AbP = SH;
  _Float16* BbP = SH + 10240;
  const int t = threadIdx.x;
  const int bid = blockIdx.x;
  const int xcd = bid & 7, slot = bid >> 3;
  const int pj = slot / 12, cc = slot % 12;
  const int p = pj * 8 + xcd;
  const int r0 = p * 128, c0 = cc * 128;

  const int ma = t >> 2, kga = t & 3;
  const _Float16* baseA[2];
  const _Float16* baseB[2];
  #pragma unroll
  for (int s = 0; s < 2; ++s) {
    baseA[s] = tok + (size_t)(r0 + ma + s * 64) * 800 + kga * 8;
    baseB[s] = qkvT + (size_t)(c0 + ma + s * 64) * 800 + kga * 8;
  }
  const int wo = ma * 40 + kga * 8;

  {
    half8 a0 = *reinterpret_cast<const half8*>(baseA[0]);
    half8 a1 = *reinterpret_cast<const half8*>(baseA[1]);
    half8 b0v = *reinterpret_cast<const half8*>(baseB[0]);
    half8 b1v = *reinterpret_cast<const half8*>(baseB[1]);
    *reinterpret_cast<half8*>(&AbP[wo]) = a0;
    *reinterpret_cast<half8*>(&AbP[wo + 2560]) = a1;
    *reinterpret_cast<half8*>(&BbP[wo]) = b0v;
    *reinterpret_cast<half8*>(&BbP[wo + 2560]) = b1v;
  }
  __syncthreads();

  const int w = t >> 6, lo = t & 15, hi = (t >> 4) & 3;
  const int wm = w >> 1, wn = w & 1;
  const int roA = (wm * 64 + lo) * 40 + 8 * hi;
  const int roB = (wn * 64 + lo) * 40 + 8 * hi;
  f32x4 acc[4][4] = {};

  for (int ck = 0; ck < 25; ++ck) {
    const int cur = ck & 1;
    const bool more = (ck + 1 < 25);
    half8 rA0, rA1, rB0, rB1;
    if (more) {
      const int kn = (ck + 1) * 32;
      rA0 = *reinterpret_cast<const half8*>(baseA[0] + kn);
      rA1 = *reinterpret_cast<const half8*>(baseA[1] + kn);
      rB0 = *reinterpret_cast<const half8*>(baseB[0] + kn);
      rB1 = *reinterpret_cast<const half8*>(baseB[1] + kn);
    }
    half8 af[4], bf[4];
    #pragma unroll
    for (int mi = 0; mi < 4; ++mi)
      af[mi] = *reinterpret_cast<const half8*>(&AbP[cur * 5120 + roA + mi * 640]);
    #pragma unroll
    for (int ni = 0; ni < 4; ++ni)
      bf[ni] = *reinterpret_cast<const half8*>(&BbP[cur * 5120 + roB + ni * 640]);
    #pragma unroll
    for (int mi = 0; mi < 4; ++mi)
      #pragma unroll
      for (int ni = 0; ni < 4; ++ni)
        acc[mi][ni] = __builtin_amdgcn_mfma_f32_16x16x32_f16(af[mi], bf[ni], acc[mi][ni], 0, 0, 0);
    if (more) {
      *reinterpret_cast<half8*>(&AbP[(cur ^ 1) * 5120 + wo]) = rA0;
      *reinterpret_cast<half8*>(&AbP[(cur ^ 1) * 5120 + wo + 2560]) = rA1;
      *reinterpret_cast<half8*>(&BbP[(cur ^ 1) * 5120 + wo]) = rB0;
      *reinterpret_cast<half8*>(&BbP[(cur ^ 1) * 5120 + wo + 2560]) = rB1;
    }
    __syncthreads();
  }

  const int seg = cc >> 2;
  const int b = r0 >> 12;
  const int m = ((r0 & 4095) >> 6) + wm;
  if (seg == 1) {
    #pragma unroll
    for (int ni = 0; ni < 4; ++ni) {
      int cl = wn * 64 + ni * 16 + lo;
      #pragma unroll
      for (int mi = 0; mi < 4; ++mi)
        #pragma unroll
        for (int rr = 0; rr < 4; ++rr) {
          int nl = wm * 64 + mi * 16 + hi * 4 + rr;
          SH[cl * 136 + nl] = (_Float16)acc[mi][ni][rr];
        }
    }
    __syncthreads();
    const int base_row = b * 512 + (cc & 3) * 128;
    const int base_n = (p & 31) * 128;
    #pragma unroll
    for (int e = t; e < 2048; e += 256) {
      int cl = e >> 4, ch = e & 15;
      half8 vvv = *reinterpret_cast<const half8*>(&SH[cl * 136 + ch * 8]);
      *reinterpret_cast<half8*>(&kTg[(size_t)(base_row + cl) * 4096 + base_n + ch * 8]) = vvv;
    }
  } else {
    const float scale = (seg == 0) ? 0.125f : 1.0f;
    _Float16* dst = (seg == 0) ? qx : vx;
    #pragma unroll
    for (int ni = 0; ni < 4; ++ni) {
      int cseg = (cc & 3) * 128 + wn * 64 + ni * 16 + lo;
      int h = cseg >> 6, d = cseg & 63;
      #pragma unroll
      for (int mi = 0; mi < 4; ++mi)
        #pragma unroll
        for (int rr = 0; rr < 4; ++rr) {
          int row = r0 + wm * 64 + mi * 16 + hi * 4 + rr;
          int nn = row & 4095;
          dst[((size_t)(b * 8 + h) * 4096 + nn) * 64 + d] = (_Float16)(acc[mi][ni][rr] * scale);
        }
    }
  }
  if (seg <= 1) {
    const float lscale = ((seg == 0) ? 0.125f : 1.0f) * (1.f / 64.f);
    #pragma unroll
    for (int ni = 0; ni < 4; ++ni) {
      float sum = 0.f;
      #pragma unroll
      for (int mi = 0; mi < 4; ++mi)
        #pragma unroll
        for (int rr = 0; rr < 4; ++rr) sum += acc[mi][ni][rr];
      sum += __shfl_xor(sum, 16);
      sum += __shfl_xor(sum, 32);
      if (hi == 0) {
        int cseg = (cc & 3) * 128 + wn * 64 + ni * 16 + lo;
        int h = cseg >> 6, d = cseg & 63;
        int bh = b * 8 + h;
        float lm = sum * lscale;
        if (seg == 0) {
          ql[((size_t)bh * 64 + m) * 64 + d] = lm;
        } else {
          kl[((size_t)bh * 64 + m) * 64 + d] = lm;
          klh[((size_t)bh * 64 + m) * 64 + d] = (_Float16)lm;
        }
      }
    }
  }
}

// ---------------- out-proj staged GEMM -> f16 lnb ----------------
__global__ __launch_bounds__(256) void k_op_s(
    const _Float16* __restrict__ attb, const _Float16* __restrict__ owT,
    const float* __restrict__ ob, _Float16* __restrict__ lnb) {
  __shared__ _Float16 Abuf[2][128 * 40];
  __shared__ _Float16 Bbuf[2][160 * 40];
  const int t = threadIdx.x;
  const int bid = blockIdx.x;
  const int xcd = bid & 7, slot = bid >> 3;
  const int pj = slot / 5, cc = slot % 5;
  const int p = pj * 8 + xcd;
  const int r0 = p * 128, c0 = cc * 160;

  const int ma = t >> 2, kga = t & 3;
  const _Float16* baseA[2];
  #pragma unroll
  for (int s = 0; s < 2; ++s)
    baseA[s] = attb + (size_t)(r0 + ma + s * 64) * 512 + kga * 8;
  const _Float16* baseB[3];
  #pragma unroll
  for (int s = 0; s < 3; ++s) {
    int cb = ma + s * 64;
    baseB[s] = owT + (size_t)(c0 + (cb < 160 ? cb : 159)) * 512 + kga * 8;
  }
  const int wo = ma * 40 + kga * 8;

  const int w = t >> 6, lo = t & 15, hi = (t >> 4) & 3;
  const int wm = w >> 1, wn = w & 1;
  const int roA = (wm * 64 + lo) * 40 + 8 * hi;
  const int roB = (wn * 80 + lo) * 40 + 8 * hi;

  f32x4 acc[4][5] = {};

  {
    half8 a0 = *reinterpret_cast<const half8*>(baseA[0]);
    half8 a1 = *reinterpret_cast<const half8*>(baseA[1]);
    half8 b0v = *reinterpret_cast<const half8*>(baseB[0]);
    half8 b1v = *reinterpret_cast<const half8*>(baseB[1]);
    *reinterpret_cast<half8*>(&Abuf[0][wo]) = a0;
    *reinterpret_cast<half8*>(&Abuf[0][wo + 2560]) = a1;
    *reinterpret_cast<half8*>(&Bbuf[0][wo]) = b0v;
    *reinterpret_cast<half8*>(&Bbuf[0][wo + 2560]) = b1v;
    if (t < 128) {
      half8 b2v = *reinterpret_cast<const half8*>(baseB[2]);
      *reinterpret_cast<half8*>(&Bbuf[0][wo + 5120]) = b2v;
    }
  }
  __syncthreads();

  for (int ck = 0; ck < 16; ++ck) {
    const int cur = ck & 1;
    const bool more = (ck + 1 < 16);
    half8 rA0, rA1, rB0, rB1, rB2;
    if (more) {
      const int kn = (ck + 1) << 5;
      rA0 = *reinterpret_cast<const half8*>(baseA[0] + kn);
      rA1 = *reinterpret_cast<const half8*>(baseA[1] + kn);
      rB0 = *reinterpret_cast<const half8*>(baseB[0] + kn);
      rB1 = *reinterpret_cast<const half8*>(baseB[1] + kn);
      if (t < 128) rB2 = *reinterpret_cast<const half8*>(baseB[2] + kn);
    }
    half8 af[4], bf[5];
    #pragma unroll
    for (int mi = 0; mi < 4; ++mi)
      af[mi] = *reinterpret_cast<const half8*>(&Abuf[cur][roA + mi * 640]);
    #pragma unroll
    for (int ni = 0; ni < 5; ++ni)
      bf[ni] = *reinterpret_cast<const half8*>(&Bbuf[cur][roB + ni * 640]);
    #pragma unroll
    for (int mi = 0; mi < 4; ++mi)
      #pragma unroll
      for (int ni = 0; ni < 5; ++ni)
        acc[mi][ni] = __builtin_amdgcn_mfma_f32_16x16x32_f16(af[mi], bf[ni], acc[mi][ni], 0, 0, 0);
    if (more) {
      *reinterpret_cast<half8*>(&Abuf[cur ^ 1][wo]) = rA0;
      *reinterpret_cast<half8*>(&Abuf[cur ^ 1][wo + 2560]) = rA1;
      *reinterpret_cast<half8*>(&Bbuf[cur ^ 1][wo]) = rB0;
      *reinterpret_cast<half8*>(&Bbuf[cur ^ 1][wo + 2560]) = rB1;
      if (t < 128) *reinterpret_cast<half8*>(&Bbuf[cur ^ 1][wo + 5120]) = rB2;
    }
    __syncthreads();
  }

  #pragma unroll
  for (int ni = 0; ni < 5; ++ni) {
    int col = c0 + wn * 80 + ni * 16 + lo;
    float bv = ob[col];
    #pragma unroll
    for (int mi = 0; mi < 4; ++mi)
      #pragma unroll
      for (int rr = 0; rr < 4; ++rr) {
        int row = r0 + wm * 64 + mi * 16 + hi * 4 + rr;
        lnb[(size_t)row * 800 + col] = (_Float16)(acc[mi][ni][rr] + bv);
      }
  }
}

// ---------------- a2 + global max row/col sums ----------------
__global__ __launch_bounds__(64) void k_a2(
    const float* __restrict__ ql, const float* __restrict__ kl,
    float* __restrict__ a2, float* __restrict__ scal) {
  __shared__ float sp[64 * 65];
  const int bh = blockIdx.x, t = threadIdx.x;
  const float* qr = ql + ((size_t)bh * 64 + t) * 64;
  const float* kb = kl + (size_t)bh * 4096;
  float mx = -1e30f;
  for (int c = 0; c < 64; ++c) {
    float acc = 0.f;
    #pragma unroll 8
    for (int dd = 0; dd < 64; ++dd) acc = fmaf(qr[dd], kb[c * 64 + dd], acc);
    sp[t * 65 + c] = acc;
    mx = fmaxf(mx, acc);
  }
  float sum = 0.f;
  for (int c = 0; c < 64; ++c) {
    float e = expf(sp[t * 65 + c] - mx);
    sp[t * 65 + c] = e;
    sum += e;
  }
  float inv = 1.f / sum;
  float rs = 0.f;
  for (int c = 0; c < 64; ++c) {
    float p = sp[t * 65 + c] * inv;
    sp[t * 65 + c] = p;
    a2[(size_t)bh * 4096 + t * 64 + c] = p;
    rs += p;
  }
  atomicMax(reinterpret_cast<int*>(scal), __float_as_int(rs));
  __syncthreads();
  float cs = 0.f;
  for (int r = 0; r < 64; ++r) cs += sp[r * 65 + t];
  atomicMax(reinterpret_cast<int*>(scal) + 1, __float_as_int(cs));
}

// ---------------- fused a3 softmax + a3@v ----------------
__global__ __launch_bounds__(256) void k_a3v(
    const float* __restrict__ ql, const _Float16* __restrict__ kT,
    const _Float16* __restrict__ vx, float* __restrict__ a3v) {
  __shared__ float sq[64];
  __shared__ float sP[4096];
  __shared__ float red[4];
  __shared__ float red2[4][64];
  const int t = threadIdx.x;
  const int m = blockIdx.x, bh = blockIdx.y;
  if (t < 64) sq[t] = ql[((size_t)bh * 64 + m) * 64 + t];
  __syncthreads();
  const _Float16* kb = kT + (size_t)bh * 262144;
  float sc[16];
  #pragma unroll
  for (int i = 0; i < 16; ++i) sc[i] = 0.f;
  for (int dd = 0; dd < 64; ++dd) {
    float qv = sq[dd];
    const half8* kr = reinterpret_cast<const half8*>(kb + (size_t)dd * 4096 + t * 16);
    half8 k0 = kr[0], k1 = kr[1];
    #pragma unroll
    for (int i = 0; i < 8; ++i) sc[i] = fmaf(qv, (float)k0[i], sc[i]);
    #pragma unroll
    for (int i = 0; i < 8; ++i) sc[8 + i] = fmaf(qv, (float)k1[i], sc[8 + i]);
  }
  float mx = sc[0];
  #pragma unroll
  for (int i = 1; i < 16; ++i) mx = fmaxf(mx, sc[i]);
  #pragma unroll
  for (int o = 32; o; o >>= 1) mx = fmaxf(mx, __shfl_xor(mx, o));
  if ((t & 63) == 0) red[t >> 6] = mx;
  __syncthreads();
  mx = fmaxf(fmaxf(red[0], red[1]), fmaxf(red[2], red[3]));
  __syncthreads();
  float sum = 0.f;
  #pragma unroll
  for (int i = 0; i < 16; ++i) {
    sc[i] = expf(sc[i] - mx);
    sum += sc[i];
  }
  #pragma unroll
  for (int o = 32; o; o >>= 1) sum += __shfl_xor(sum, o);
  if ((t & 63) == 0) red[t >> 6] = sum;
  __syncthreads();
  sum = red[0] + red[1] + red[2] + red[3];
  float inv = 1.f / sum;
  #pragma unroll
  for (int i = 0; i < 16; ++i) sP[t * 16 + i] = sc[i] * inv;
  __syncthreads();
  const int seg = t >> 6, l = t & 63;
  const int nl = l >> 3, dblk = (l & 7) * 8;
  const _Float16* vb = vx + (size_t)bh * 262144;
  float acc8[8] = {};
  for (int it = 0; it < 128; ++it) {
    int n8 = seg * 1024 + it * 8;
    half8 vv = *reinterpret_cast<const half8*>(&vb[(size_t)(n8 + nl) * 64 + dblk]);
    float pc = sP[n8 + nl];
    #pragma unroll
    for (int u = 0; u < 8; ++u) acc8[u] = fmaf(pc, (float)vv[u], acc8[u]);
  }
  #pragma unroll
  for (int off = 8; off <= 32; off <<= 1)
    #pragma unroll
    for (int u = 0; u < 8; ++u) acc8[u] += __shfl_xor(acc8[u], off);
  if (nl == 0) {
    #pragma unroll
    for (int u = 0; u < 8; ++u) red2[seg][dblk + u] = acc8[u];
  }
  __syncthreads();
  if (seg == 0)
    a3v[((size_t)bh * 64 + m) * 64 + l] = red2[0][l] + red2[1][l] + red2[2][l] + red2[3][l];
}

// ---------------- Moore-Penrose pinv + fused w2t ----------------
__global__ __launch_bounds__(256) void k_pinv(
    const float* __restrict__ a2g, const float* __restrict__ scal,
    const float* __restrict__ a3vg, _Float16* __restrict__ w2t) {
  __shared__ float z[64 * 68];
  __shared__ float az[64 * 68];
  __shared__ float tb[64 * 68];
  const int bh = blockIdx.x, t = threadIdx.x;
  const int r0 = (t >> 4) << 2, c0 = (t & 15) << 2;
  const float* ag = a2g + (size_t)bh * 4096;
  const float denom = 1.f / (scal[0] * scal[1]);
  #pragma unroll
  for (int i = 0; i < 4; ++i)
    #pragma unroll
    for (int j = 0; j < 4; ++j)
      z[(r0 + i) * 68 + c0 + j] = ag[(c0 + j) * 64 + r0 + i] * denom;
  __syncthreads();
  float reg[4][4], val[4][4];
  for (int it = 0; it < 6; ++it) {
    mm16v<64, 68>(ag, z, r0, c0, reg);
    #pragma unroll
    for (int i = 0; i < 4; ++i)
      #pragma unroll
      for (int j = 0; j < 4; ++j) az[(r0 + i) * 68 + c0 + j] = reg[i][j];
    __syncthreads();
    mm16v<68, 68>(az, az, r0, c0, reg);
    #pragma unroll
    for (int i = 0; i < 4; ++i)
      #pragma unroll
      for (int j = 0; j < 4; ++j)
        tb[(r0 + i) * 68 + c0 + j] = 7.f * az[(r0 + i) * 68 + c0 + j] - reg[i][j];
    __syncthreads();
    mm16v<68, 68>(az, tb, r0, c0, reg);
    #pragma unroll
    for (int i = 0; i < 4; ++i)
      #pragma unroll
      for (int j = 0; j < 4; ++j)
        val[i][j] = 15.f * az[(r0 + i) * 68 + c0 + j] - reg[i][j];
    __syncthreads();
    #pragma unroll
    for (int i = 0; i < 4; ++i)
      #pragma unroll
      for (int j = 0; j < 4; ++j) tb[(r0 + i) * 68 + c0 + j] = val[i][j];
    __syncthreads();
    mm16v<68, 68>(z, tb, r0, c0, reg);
    #pragma unroll
    for (int i = 0; i < 4; ++i)
      #pragma unroll
      for (int j = 0; j < 4; ++j)
        val[i][j] = 0.25f * (13.f * z[(r0 + i) * 68 + c0 + j] - reg[i][j]);
    __syncthreads();
    #pragma unroll
    for (int i = 0; i < 4; ++i)
      #pragma unroll
      for (int j = 0; j < 4; ++j) z[(r0 + i) * 68 + c0 + j] = val[i][j];
    __syncthreads();
  }
  mm16v<68, 64>(z, a3vg + (size_t)bh * 4096, r0, c0, reg);
  #pragma unroll
  for (int i = 0; i < 4; ++i)
    #pragma unroll
    for (int j = 0; j < 4; ++j)
      w2t[(size_t)bh * 4096 + (c0 + j) * 64 + (r0 + i)] = (_Float16)reg[i][j];
}

// ------- fused MFMA combine ------------
__global__ __launch_bounds__(256) void k_combine_m(
    const _Float16* __restrict__ qx, const _Float16* __restrict__ klh,
    const _Float16* __restrict__ w2t, const _Float16* __restrict__ vx,
    const float* __restrict__ rw, _Float16* __restrict__ att) {
  __shared__ _Float16 sP[64 * 72];
  __shared__ _Float16 sVT[64 * 104];
  __shared__ _Float16 sT[64 * 104];
  __shared__ float sR[33];
  const int t = threadIdx.x, w = t >> 6, lo = t & 15, hi = (t >> 4) & 3;
  const int n0 = blockIdx.x * 64;
  const int h = blockIdx.y, b = blockIdx.z, bh = b * 8 + h;
  if (t < 33) sR[t] = rw[h * 33 + t];
  __syncthreads();
  const _Float16* vb = vx + (size_t)bh * 262144;
  #pragma unroll
  for (int u = 0; u < 24; ++u) {
    int e = t + u * 256;
    int r = e >> 6, d = e & 63;
    int nn = n0 - 16 + r;
    sVT[d * 104 + r] = ((unsigned)nn < 4096u) ? vb[(size_t)nn * 64 + d] : (_Float16)0.f;
  }
  #pragma unroll
  for (int u = 0; u < 24; ++u) {
    int e = t + u * 256;
    int r = e % 96, i = e / 96;
    int j = r - i;
    sT[i * 104 + r] = (j >= 0 && j < 33) ? (_Float16)sR[j] : (_Float16)0.f;
  }
  f32x4 sa[4] = {};
  const _Float16* qp = qx + ((size_t)bh * 4096 + n0 + w * 16 + lo) * 64 + 8 * hi;
  const _Float16* klp = klh + (size_t)bh * 4096;
  #pragma unroll
  for (int c = 0; c < 2; ++c) {
    half8 a = *reinterpret_cast<const half8*>(qp + 32 * c);
    #pragma unroll
    for (int ct = 0; ct < 4; ++ct) {
      half8 bf = *reinterpret_cast<const half8*>(klp + (size_t)(ct * 16 + lo) * 64 + 8 * hi + 32 * c);
      sa[ct] = __builtin_amdgcn_mfma_f32_16x16x32_f16(a, bf, sa[ct], 0, 0, 0);
    }
  }
  #pragma unroll
  for (int r = 0; r < 4; ++r) {
    float mx = fmaxf(fmaxf(sa[0][r], sa[1][r]), fmaxf(sa[2][r], sa[3][r]));
    #pragma unroll
    for (int o = 8; o; o >>= 1) mx = fmaxf(mx, __shfl_xor(mx, o));
    float e0 = expf(sa[0][r] - mx), e1 = expf(sa[1][r] - mx);
    float e2 = expf(sa[2][r] - mx), e3 = expf(sa[3][r] - mx);
    float sm = e0 + e1 + e2 + e3;
    #pragma unroll
    for (int o = 8; o; o >>= 1) sm += __shfl_xor(sm, o);
    float inv = 1.f / sm;
    int row = w * 16 + hi * 4 + r;
    sP[row * 72 + lo] = (_Float16)(e0 * inv);
    sP[row * 72 + 16 + lo] = (_Float16)(e1 * inv);
    sP[row * 72 + 32 + lo] = (_Float16)(e2 * inv);
    sP[row * 72 + 48 + lo] = (_Float16)(e3 * inv);
  }
  __syncthreads();
  f32x4 ao[4] = {};
  const _Float16* w2p = w2t + (size_t)bh * 4096;
  #pragma unroll
  for (int c = 0; c < 2; ++c) {
    half8 a = *reinterpret_cast<const half8*>(&sP[(w * 16 + lo) * 72 + 8 * hi + 32 * c]);
    #pragma unroll
    for (int ct = 0; ct < 4; ++ct) {
      half8 bf = *reinterpret_cast<const half8*>(w2p + (size_t)(ct * 16 + lo) * 64 + 8 * hi + 32 * c);
      ao[ct] = __builtin_amdgcn_mfma_f32_16x16x32_f16(a, bf, ao[ct], 0, 0, 0);
    }
  }
  #pragma unroll
  for (int c = 0; c < 3; ++c) {
    half8 a = *reinterpret_cast<const half8*>(&sT[(w * 16 + lo) * 104 + 8 * hi + 32 * c]);
    #pragma unroll
    for (int ct = 0; ct < 4; ++ct) {
      half8 bf = *reinterpret_cast<const half8*>(&sVT[(ct * 16 + lo) * 104 + 8 * hi + 32 * c]);
      ao[ct] = __builtin_amdgcn_mfma_f32_16x16x32_f16(a, bf, ao[ct], 0, 0, 0);
    }
  }
  _Float16* ab = att + ((size_t)b * 4096) * 512 + (size_t)h * 64;
  #pragma unroll
  for (int ct = 0; ct < 4; ++ct)
    #pragma unroll
    for (int r = 0; r < 4; ++r) {
      int n = n0 + w * 16 + hi * 4 + r;
      ab[(size_t)n * 512 + ct * 16 + lo] = (_Float16)ao[ct][r];
    }
}

// ---------------- fused LayerNorm + head MFMA ----------------
__global__ __launch_bounds__(256) void k_lnhead(
    const _Float16* __restrict__ ln, const _Float16* __restrict__ hwh,
    const float* __restrict__ g, const float* __restrict__ bb,
    const float* __restrict__ hb, float* __restrict__ out) {
  const int t = threadIdx.x, w = t >> 6, lo = t & 15, hi = (t >> 4) & 3;
  const int row0 = blockIdx.x * 64 + w * 16;
  const _Float16* ap = ln + (size_t)(row0 + lo) * 800 + 8 * hi;
  float s1 = 0.f, s2 = 0.f;
  #pragma unroll 5
  for (int k = 0; k < 800; k += 32) {
    half8 a = *reinterpret_cast<const half8*>(ap + k);
    #pragma unroll
    for (int u = 0; u < 8; ++u) {
      float x = (float)a[u];
      s1 += x;
      s2 = fmaf(x, x, s2);
    }
  }
  s1 += __shfl_xor(s1, 16); s1 += __shfl_xor(s1, 32);
  s2 += __shfl_xor(s2, 16); s2 += __shfl_xor(s2, 32);
  float mean = s1 * (1.f / 800.f);
  float var = s2 * (1.f / 800.f) - mean * mean;
  float rstd = rsqrtf(var + LN_EPS_C);
  const _Float16* bp = hwh + (size_t)lo * 800 + 8 * hi;
  f32x4 acc = {};
  #pragma unroll 5
  for (int k = 0; k < 800; k += 32) {
    half8 a = *reinterpret_cast<const half8*>(ap + k);
    half8 an;
    #pragma unroll
    for (int u = 0; u < 8; ++u) {
      int kk = k + 8 * hi + u;
      float x = ((float)a[u] - mean) * rstd * g[kk] + bb[kk];
      an[u] = (_Float16)x;
    }
    half8 b = *reinterpret_cast<const half8*>(bp + k);
    acc = __builtin_amdgcn_mfma_f32_16x16x32_f16(an, b, acc, 0, 0, 0);
  }
  float bv = hb[lo];
  #pragma unroll
  for (int r = 0; r < 4; ++r) {
    int row = row0 + hi * 4 + r;
    out[(size_t)row * 16 + lo] = 1.f / (1.f + expf(-(acc[r] + bv)));
  }
}

// ---------------- launcher ----------------
extern "C" void kernel_launch(void* const* d_in, const int* in_sizes, int n_in,
                              void* d_out, int out_size, void* d_ws, size_t ws_size,
                              hipStream_t stream) {
  (void)in_sizes; (void)n_in; (void)out_size; (void)ws_size;
  const float* x     = (const float*)d_in[0];
  const float* w0    = (const float*)d_in[1];
  const float* b0    = (const float*)d_in[2];
  const float* g0    = (const float*)d_in[3];
  const float* be0   = (const float*)d_in[4];
  const float* mu0   = (const float*)d_in[5];
  const float* var0  = (const float*)d_in[6];
  const float* w1    = (const float*)d_in[7];
  const float* b1    = (const float*)d_in[8];
  const float* g1    = (const float*)d_in[9];
  const float* be1   = (const float*)d_in[10];
  const float* mu1   = (const float*)d_in[11];
  const float* var1  = (const float*)d_in[12];
  const float* w2c   = (const float*)d_in[13];
  const float* b2    = (const float*)d_in[14];
  const float* g2    = (const float*)d_in[15];
  const float* be2   = (const float*)d_in[16];
  const float* mu2   = (const float*)d_in[17];
  const float* var2  = (const float*)d_in[18];
  const float* w3    = (const float*)d_in[19];
  const float* b3    = (const float*)d_in[20];
  const float* g3    = (const float*)d_in[21];
  const float* be3   = (const float*)d_in[22];
  const float* mu3   = (const float*)d_in[23];
  const float* var3  = (const float*)d_in[24];
  const float* qkvw  = (const float*)d_in[25];
  const float* outw  = (const float*)d_in[26];
  const float* outbv = (const float*)d_in[27];
  const float* resw  = (const float*)d_in[28];
  const float* lng   = (const float*)d_in[29];
  const float* lnbv  = (const float*)d_in[30];
  const float* headw = (const float*)d_in[31];
  const float* headb = (const float*)d_in[32];

  char* wsb = (char*)d_ws;
  _Float16* h0   = (_Float16*)(wsb + B_H0);
  _Float16* h1   = (_Float16*)(wsb + B_H1);
  _Float16* h2   = (_Float16*)(wsb + B_H2);
  _Float16* qb   = (_Float16*)(wsb + B_Q);
  _Float16* vb   = (_Float16*)(wsb + B_V);
  _Float16* kT   = (_Float16*)(wsb + B_KT);
  _Float16* tok  = (_Float16*)(wsb + B_TOK);
  _Float16* attb = (_Float16*)(wsb + B_ATT);
  _Float16* wp1  = (_Float16*)(wsb + B_WP1);
  _Float16* wp2  = (_Float16*)(wsb + B_WP2);
  _Float16* wp3  = (_Float16*)(wsb + B_WP3);
  _Float16* qkvT = (_Float16*)(wsb + B_QKVT);
  _Float16* owT  = (_Float16*)(wsb + B_OWT);
  _Float16* klh  = (_Float16*)(wsb + B_KLH);
  _Float16* w2t  = (_Float16*)(wsb + B_W2T);
  _Float16* hwh  = (_Float16*)(wsb + B_HWH);
  _Float16* lnb16 = (_Float16*)(wsb + B_LNB);
  float* ql   = (float*)(wsb + B_QL);
  float* kl   = (float*)(wsb + B_KL);
  float* a2   = (float*)(wsb + B_A2);
  float* a3v  = (float*)(wsb + B_A3V);
  float* scal = (float*)(wsb + B_SCAL);

  k_pack_all<<<dim3(20691), 256, 0, stream>>>(
      w1, w2c, w3, qkvw, outw, headw, wp1, wp2, wp3, qkvT, owT, hwh, scal);

  for (int img = 0; img < 4; ++img) {
    k_conv0<<<dim3(256, 4), 256, 0, stream>>>(
        x + (size_t)img * 65536, w0, b0, g0, be0, mu0, var0, h0);
    k_convs<64><<<dim3(512), 256, 0, stream>>>(
        h0, wp1, b1, g1, be1, mu1, var1, h1, 128, 1);
    k_convs<128><<<dim3(1024), 256, 0, stream>>>(
        h1, wp2, b2, g2, be2, mu2, var2, h2 + (size_t)img * 16777216, 256, 2);
  }
  k_c3<<<dim3(640), 256, 0, stream>>>(h2, wp3, b3, g3, be3, mu3, var3, tok);
  k_qkv_s<<<dim3(1536), 256, 0, stream>>>(tok, qkvT, qb, kT, vb, ql, kl, klh);
  k_a2<<<dim3(32), 64, 0, stream>>>(ql, kl, a2, scal);
  k_a3v<<<dim3(64, 32), 256, 0, stream>>>(ql, kT, vb, a3v);
  k_pinv<<<dim3(32), 256, 0, stream>>>(a2, scal, a3v, w2t);
  k_combine_m<<<dim3(64, 8, 4), 256, 0, stream>>>(qb, klh, w2t, vb, resw, attb);
  k_op_s<<<dim3(640), 256, 0, stream>>>(attb, owT, outbv, lnb16);
  k_lnhead<<<dim3(256), 256, 0, stream>>>(lnb16, hwh, lng, lnbv, headb, (float*)d_out);
}

// Round 15
// 938.321 us; speedup vs baseline: 1.0172x; 1.0021x over previous
//
#include <hip/hip_runtime.h>

#define DI __device__ __forceinline__

constexpr float BN_EPS_C = 1e-5f;
constexpr float LN_EPS_C = 1e-5f;

typedef _Float16 half8 __attribute__((ext_vector_type(8)));
typedef float f32x4 __attribute__((ext_vector_type(4)));

// ---------------- workspace layout (BYTE offsets), peak ~199.34 MB ----------------
constexpr size_t B_H0   = 0;
constexpr size_t B_H1   = 8388608;
constexpr size_t B_H2   = 25165824;      // f16 [4][256][256][256] = 134,217,728
constexpr size_t B_Q    = 25165824;
constexpr size_t B_V    = 58720256;
constexpr size_t B_KT   = 75497472;
constexpr size_t B_ATT  = 92274688;
constexpr size_t B_LNB  = 25165824;
constexpr size_t B_TOK  = 159383552;
constexpr size_t B_WP1  = 185597952;
constexpr size_t B_WP2  = 185745408;
constexpr size_t B_WP3  = 186335232;
constexpr size_t B_QKVT = 192888832;
constexpr size_t B_OWT  = 195346432;
constexpr size_t B_QL   = 196165632;
constexpr size_t B_KL   = 196689920;
constexpr size_t B_KLH  = 197214208;
constexpr size_t B_A2   = 197476352;
constexpr size_t B_W2T  = 198524928;
constexpr size_t B_A3V  = 198787072;
constexpr size_t B_SCAL = 199311360;
constexpr size_t B_HWH  = 199311424;     // end 199,337,024
constexpr size_t B_ZPG  = 199337024;     // 32-byte zero page (end 199,337,056)

// ---------------- helpers ----------------
DI void gl_lds16(const _Float16* g, _Float16* l) {
  __builtin_amdgcn_global_load_lds(
      (const __attribute__((address_space(1))) void*)g,
      (__attribute__((address_space(3))) void*)l, 16, 0, 0);
}

template <int LP, int RP>
DI void mm16v(const float* L, const float* R, int r0, int c0, float reg[4][4]) {
  #pragma unroll
  for (int i = 0; i < 4; ++i)
    #pragma unroll
    for (int j = 0; j < 4; ++j) reg[i][j] = 0.f;
  #pragma unroll 4
  for (int dd = 0; dd < 64; dd += 4) {
    f32x4 l[4], rv[4];
    #pragma unroll
    for (int i = 0; i < 4; ++i)
      l[i] = *reinterpret_cast<const f32x4*>(&L[(size_t)(r0 + i) * LP + dd]);
    #pragma unroll
    for (int u = 0; u < 4; ++u)
      rv[u] = *reinterpret_cast<const f32x4*>(&R[(size_t)(dd + u) * RP + c0]);
    #pragma unroll
    for (int i = 0; i < 4; ++i)
      #pragma unroll
      for (int u = 0; u < 4; ++u)
        #pragma unroll
        for (int j = 0; j < 4; ++j)
          reg[i][j] = fmaf(l[i][u], rv[u][j], reg[i][j]);
  }
}

// ---------------- mega-pack (+ zero page) ----------------
__global__ void k_pack_all(
    const float* __restrict__ w1, const float* __restrict__ w2c, const float* __restrict__ w3,
    const float* __restrict__ qkvw, const float* __restrict__ outw, const float* __restrict__ headw,
    _Float16* __restrict__ wp1, _Float16* __restrict__ wp2, _Float16* __restrict__ wp3,
    _Float16* __restrict__ qkvT, _Float16* __restrict__ owT, _Float16* __restrict__ hwh,
    float* __restrict__ scal, float* __restrict__ zpg) {
  size_t i = (size_t)blockIdx.x * 256 + threadIdx.x;
  if (i < 73728) {
    int q = i % 9, ci = (i / 9) % 64, co = i / (9 * 64);
    wp1[((size_t)co * 9 + q) * 64 + ci] = (_Float16)w1[i];
  } else if (i < 368640) {
    size_t j = i - 73728;
    int q = j % 9, ci = (j / 9) % 128, co = j / (9 * 128);
    wp2[((size_t)co * 9 + q) * 128 + ci] = (_Float16)w2c[j];
  } else if (i < 3645440) {
    size_t j = i - 368640;
    int q = j % 16, ci = (j / 16) % 256, co = j / (16 * 256);
    wp3[((size_t)co * 16 + q) * 256 + ci] = (_Float16)w3[j];
  } else if (i < 4874240) {
    size_t j = i - 3645440;
    int n = j % 1536, k = j / 1536;
    qkvT[(size_t)n * 800 + k] = (_Float16)qkvw[j];
  } else if (i < 5283840) {
    size_t j = i - 4874240;
    int n = j % 800, k = j / 800;
    owT[(size_t)n * 512 + k] = (_Float16)outw[j];
  } else if (i < 5296640) {
    size_t j = i - 5283840;
    int n = j % 16, k = j / 16;
    hwh[(size_t)n * 800 + k] = (_Float16)headw[j];
  } else if (i < 5296642) {
    scal[i - 5296640] = 0.f;
  } else if (i < 5296650) {
    zpg[i - 5296642] = 0.f;
  }
}

// ---------------- conv0 ----------------
__global__ __launch_bounds__(256) void k_conv0(
    const float* __restrict__ xb, const float* __restrict__ w0, const float* __restrict__ b0,
    const float* __restrict__ g0, const float* __restrict__ be0, const float* __restrict__ mu0,
    const float* __restrict__ var0, _Float16* __restrict__ h0) {
  const int t = threadIdx.x, co = t & 63, xg = t >> 6;
  const int y = blockIdx.x;
  const int x0 = blockIdx.y * 64 + xg * 16;
  float wreg[9];
  #pragma unroll
  for (int q = 0; q < 9; ++q) wreg[q] = w0[co * 9 + q];
  float s = g0[co] * rsqrtf(var0[co] + BN_EPS_C);
  float sh = fmaf(b0[co] - mu0[co], s, be0[co]);
  #pragma unroll 4
  for (int xl = 0; xl < 16; ++xl) {
    int xx = x0 + xl;
    float acc = 0.f;
    #pragma unroll
    for (int dy = 0; dy < 3; ++dy) {
      int yy = y + dy - 1;
      if ((unsigned)yy >= 256u) continue;
      #pragma unroll
      for (int dx = 0; dx < 3; ++dx) {
        int xi = xx + dx - 1;
        if ((unsigned)xi >= 256u) continue;
        acc = fmaf(wreg[dy * 3 + dx], xb[yy * 256 + xi], acc);
      }
    }
    float v = fmaxf(fmaf(acc, s, sh), 0.f);
    h0[((size_t)y * 256 + xx) * 64 + co] = (_Float16)v;
  }
}

// ------- staged implicit-im2col 3x3 conv GEMM via global_load_lds (zero-page halo) --------
template <int CI>
__global__ __launch_bounds__(256) void k_convs(
    const _Float16* __restrict__ in, const _Float16* __restrict__ wp,
    const float* __restrict__ bias, const float* __restrict__ g, const float* __restrict__ be,
    const float* __restrict__ mu, const float* __restrict__ var,
    _Float16* __restrict__ out, int CO, int NCT, const _Float16* __restrict__ zpg) {
  __shared__ _Float16 Ab[2][128 * 32];
  __shared__ _Float16 Bb[2][128 * 32];
  constexpr int CPQ = CI / 32;
  constexpr int NCK = 9 * CPQ;
  const int t = threadIdx.x;
  const int bid = blockIdx.x;
  const int xcd = bid & 7, slot = bid >> 3;
  const int pj = slot / NCT, cc = slot % NCT;
  const int p = pj * 8 + xcd;
  const int r0 = p * 128, c0 = cc * 128;

  const int w = t >> 6, l = t & 63;
  const int kslot = (l & 3) ^ ((l >> 3) & 3);
  int ry[2], rx[2];
  #pragma unroll
  for (int s = 0; s < 2; ++s) {
    int r = r0 + 16 * w + (l >> 2) + 64 * s;
    ry[s] = r >> 8;
    rx[s] = r & 255;
  }
  const _Float16* gB[2];
  #pragma unroll
  for (int s = 0; s < 2; ++s)
    gB[s] = wp + (size_t)(c0 + 16 * w + (l >> 2) + 64 * s) * 9 * CI + kslot * 8;

  const int lo = t & 15, hi = (t >> 4) & 3;
  const int wm = w >> 1, wn = w & 1;
  const int sl = hi ^ ((lo >> 1) & 3);
  const int roA = (wm * 64 + lo) * 32 + sl * 8;
  const int roB = (wn * 64 + lo) * 32 + sl * 8;
  f32x4 acc[4][4] = {};

  auto STAGE = [&](int buf, int ck) {
    const int q = ck / CPQ, coff = (ck % CPQ) * 32;
    const int dy = q / 3 - 1, dx = q % 3 - 1;
    _Float16* Ad = &Ab[buf][512 * w];
    _Float16* Bd = &Bb[buf][512 * w];
    #pragma unroll
    for (int s = 0; s < 2; ++s) {
      int yy = ry[s] + dy, xx = rx[s] + dx;
      const _Float16* src =
          ((unsigned)yy < 256u && (unsigned)xx < 256u)
              ? in + ((size_t)yy * 256 + xx) * CI + coff + kslot * 8
              : zpg;
      gl_lds16(src, Ad + s * 2048);
    }
    gl_lds16(gB[0] + ck * 32, Bd);
    gl_lds16(gB[1] + ck * 32, Bd + 2048);
  };

  STAGE(0, 0);
  __syncthreads();

  for (int ck = 0; ck < NCK; ++ck) {
    const int cur = ck & 1;
    if (ck + 1 < NCK) STAGE(cur ^ 1, ck + 1);
    half8 af[4], bf[4];
    #pragma unroll
    for (int mi = 0; mi < 4; ++mi)
      af[mi] = *reinterpret_cast<const half8*>(&Ab[cur][roA + mi * 512]);
    #pragma unroll
    for (int ni = 0; ni < 4; ++ni)
      bf[ni] = *reinterpret_cast<const half8*>(&Bb[cur][roB + ni * 512]);
    #pragma unroll
    for (int mi = 0; mi < 4; ++mi)
      #pragma unroll
      for (int ni = 0; ni < 4; ++ni)
        acc[mi][ni] = __builtin_amdgcn_mfma_f32_16x16x32_f16(af[mi], bf[ni], acc[mi][ni], 0, 0, 0);
    __syncthreads();
  }

  #pragma unroll
  for (int ni = 0; ni < 4; ++ni) {
    int co = c0 + wn * 64 + ni * 16 + lo;
    float s = g[co] * rsqrtf(var[co] + BN_EPS_C);
    float sh = fmaf(bias[co] - mu[co], s, be[co]);
    #pragma unroll
    for (int mi = 0; mi < 4; ++mi)
      #pragma unroll
      for (int rr = 0; rr < 4; ++rr) {
        int row = r0 + wm * 64 + mi * 16 + hi * 4 + rr;
        float v = fmaxf(fmaf(acc[mi][ni][rr], s, sh), 0.f);
        out[(size_t)row * CO + co] = (_Float16)v;
      }
  }
}

// ------- conv3: staged GEMM 128x160 via global_load_lds (r14 proven) ---
__global__ __launch_bounds__(256) void k_c3(
    const _Float16* __restrict__ h2, const _Float16* __restrict__ wp3,
    const float* __restrict__ b3, const float* __restrict__ g3, const float* __restrict__ be3,
    const float* __restrict__ mu3, const float* __restrict__ var3,
    _Float16* __restrict__ tok) {
  __shared__ _Float16 Abuf[2][128 * 32];
  __shared__ _Float16 Bbuf[2][160 * 32];
  const int t = threadIdx.x;
  const int bid = blockIdx.x;
  const int xcd = bid & 7, slot = bid >> 3;
  const int pj = slot / 5, cc = slot % 5;
  const int p = pj * 8 + xcd;
  const int r0 = p * 128, c0 = cc * 160;
  const int img = r0 >> 12;
  const _Float16* h2i = h2 + (size_t)img * 16777216;

  const int w = t >> 6, l = t & 63;
  const int kslot = (l & 3) ^ ((l >> 3) & 3);
  const _Float16* gA[2];
  #pragma unroll
  for (int s = 0; s < 2; ++s) {
    int mar = 16 * w + (l >> 2) + 64 * s;
    int r = r0 + mar;
    int py = (r & 4095) >> 6, px = r & 63;
    gA[s] = h2i + ((size_t)py * 1024 + px * 4) * 256 + kslot * 8;
  }
  const _Float16* gB[3];
  #pragma unroll
  for (int s = 0; s < 3; ++s) {
    int rb = 16 * w + (l >> 2) + 64 * s;
    if (rb > 159) rb = 159;
    gB[s] = wp3 + (size_t)(c0 + rb) * 4096 + kslot * 8;
  }

  const int lo = t & 15, hi = (t >> 4) & 3;
  const int wm = w >> 1, wn = w & 1;
  const int sl = hi ^ ((lo >> 1) & 3);
  const int roA = (wm * 64 + lo) * 32 + sl * 8;
  const int roB = (wn * 80 + lo) * 32 + sl * 8;

  f32x4 acc[4][5] = {};

  auto STAGE = [&](int buf, int ck) {
    const int kn = ck << 5;
    const int q = kn >> 8;
    const size_t aoff = (size_t)(q >> 2) * 65536 + (size_t)(q & 3) * 256 + (kn & 255);
    _Float16* Ad = &Abuf[buf][512 * w];
    _Float16* Bd = &Bbuf[buf][512 * w];
    gl_lds16(gA[0] + aoff, Ad);
    gl_lds16(gA[1] + aoff, Ad + 2048);
    gl_lds16(gB[0] + kn, Bd);
    gl_lds16(gB[1] + kn, Bd + 2048);
    if (w < 2) gl_lds16(gB[2] + kn, Bd + 4096);
  };

  STAGE(0, 0);
  __syncthreads();

  for (int ck = 0; ck < 128; ++ck) {
    const int cur = ck & 1;
    if (ck + 1 < 128) STAGE(cur ^ 1, ck + 1);
    half8 af[4], bf[5];
    #pragma unroll
    for (int mi = 0; mi < 4; ++mi)
      af[mi] = *reinterpret_cast<const half8*>(&Abuf[cur][roA + mi * 512]);
    #pragma unroll
    for (int ni = 0; ni < 5; ++ni)
      bf[ni] = *reinterpret_cast<const half8*>(&Bbuf[cur][roB + ni * 512]);
    #pragma unroll
    for (int mi = 0; mi < 4; ++mi)
      #pragma unroll
      for (int ni = 0; ni < 5; ++ni)
        acc[mi][ni] = __builtin_amdgcn_mfma_f32_16x16x32_f16(af[mi], bf[ni], acc[mi][ni], 0, 0, 0);
    __syncthreads();
  }

  #pragma unroll
  for (int ni = 0; ni < 5; ++ni) {
    int col = c0 + wn * 80 + ni * 16 + lo;
    float s = g3[col] * rsqrtf(var3[col] + BN_EPS_C);
    float sh = fmaf(b3[col] - mu3[col], s, be3[col]);
    #pragma unroll
    for (int mi = 0; mi < 4; ++mi)
      #pragma unroll
      for (int rr = 0; rr < 4; ++rr) {
        int row = r0 + wm * 64 + mi * 16 + hi * 4 + rr;
        float v = fmaxf(fmaf(acc[mi][ni][rr], s, sh), 0.f);
        tok[(size_t)row * 800 + col] = (_Float16)v;
      }
  }
}

// ---------------- qkv via global_load_lds + fused landmarks; kT via LDS transpose ---------
__global__ __launch_bounds__(256) void k_qkv_s(
    const _Float16* __restrict__ tok, const _Float16* __restrict__ qkvT,
    _Float16* __restrict__ qx, _Float16* __restrict__ kTg, _Float16* __restrict__ vx,
    float* __restrict__ ql, float* __restrict__ kl, _Float16* __restrict__ klh) {
  __shared__ _Float16 SH[17408];           // staging: Ab 2x4096 | Bb 2x4096; transpose: 128x136
  _Float16* AbP = SH;
  _Float16* BbP = SH + 8192;
  const int t = threadIdx.x;
  const int bid = blockIdx.x;
  const int xcd = bid & 7, slot = bid >> 3;
  const int pj = slot / 12, cc = slot % 12;
  const int p = pj * 8 + xcd;
  const int r0 = p * 128, c0 = cc * 128;

  const int w = t >> 6, l = t & 63;
  const int kslot = (l & 3) ^ ((l >> 3) & 3);
  const _Float16* gA[2];
  const _Float16* gB[2];
  #pragma unroll
  for (int s = 0; s < 2; ++s) {
    int mar = 16 * w + (l >> 2) + 64 * s;
    gA[s] = tok + (size_t)(r0 + mar) * 800 + kslot * 8;
    gB[s] = qkvT + (size_t)(c0 + mar) * 800 + kslot * 8;
  }

  const int lo = t & 15, hi = (t >> 4) & 3;
  const int wm = w >> 1, wn = w & 1;
  const int sl = hi ^ ((lo >> 1) & 3);
  const int roA = (wm * 64 + lo) * 32 + sl * 8;
  const int roB = (wn * 64 + lo) * 32 + sl * 8;
  f32x4 acc[4][4] = {};

  auto STAGE = [&](int buf, int ck) {
    const int kn = ck * 32;
    _Float16* Ad = &AbP[buf * 4096 + 512 * w];
    _Float16* Bd = &BbP[buf * 4096 + 512 * w];
    gl_lds16(gA[0] + kn, Ad);
    gl_lds16(gA[1] + kn, Ad + 2048);
    gl_lds16(gB[0] + kn, Bd);
    gl_lds16(gB[1] + kn, Bd + 2048);
  };

  STAGE(0, 0);
  __syncthreads();

  for (int ck = 0; ck < 25; ++ck) {
    const int cur = ck & 1;
    if (ck + 1 < 25) STAGE(cur ^ 1, ck + 1);
    half8 af[4], bf[4];
    #pragma unroll
    for (int mi = 0; mi < 4; ++mi)
      af[mi] = *reinterpret_cast<const half8*>(&AbP[cur * 4096 + roA + mi * 512]);
    #pragma unroll
    for (int ni = 0; ni < 4; ++ni)
      bf[ni] = *reinterpret_cast<const half8*>(&BbP[cur * 4096 + roB + ni * 512]);
    #pragma unroll
    for (int mi = 0; mi < 4; ++mi)
      #pragma unroll
      for (int ni = 0; ni < 4; ++ni)
        acc[mi][ni] = __builtin_amdgcn_mfma_f32_16x16x32_f16(af[mi], bf[ni], acc[mi][ni], 0, 0, 0);
    __syncthreads();
  }

  const int seg = cc >> 2;
  const int b = r0 >> 12;
  const int m = ((r0 & 4095) >> 6) + wm;
  if (seg == 1) {
    #pragma unroll
    for (int ni = 0; ni < 4; ++ni) {
      int cl = wn * 64 + ni * 16 + lo;
      #pragma unroll
      for (int mi = 0; mi < 4; ++mi)
        #pragma unroll
        for (int rr = 0; rr < 4; ++rr) {
          int nl = wm * 64 + mi * 16 + hi * 4 + rr;
          SH[cl * 136 + nl] = (_Float16)acc[mi][ni][rr];
        }
    }
    __syncthreads();
    const int base_row = b * 512 + (cc & 3) * 128;
    const int base_n = (p & 31) * 128;
    #pragma unroll
    for (int e = t; e < 2048; e += 256) {
      int cl = e >> 4, ch = e & 15;
      half8 vvv = *reinterpret_cast<const half8*>(&SH[cl * 136 + ch * 8]);
      *reinterpret_cast<half8*>(&kTg[(size_t)(base_row + cl) * 4096 + base_n + ch * 8]) = vvv;
    }
  } else {
    const float scale = (seg == 0) ? 0.125f : 1.0f;
    _Float16* dst = (seg == 0) ? qx : vx;
    #pragma unroll
    for (int ni = 0; ni < 4; ++ni) {
      int cseg = (cc & 3) * 128 + wn * 64 + ni * 16 + lo;
      int h = cseg >> 6, d = cseg & 63;
      #pragma unroll
      for (int mi = 0; mi < 4; ++mi)
        #pragma unroll
        for (int rr = 0; rr < 4; ++rr) {
          int row = r0 + wm * 64 + mi * 16 + hi * 4 + rr;
          int nn = row & 4095;
          dst[((size_t)(b * 8 + h) * 4096 + nn) * 64 + d] = (_Float16)(acc[mi][ni][rr] * scale);
        }
    }
  }
  if (seg <= 1) {
    const float lscale = ((seg == 0) ? 0.125f : 1.0f) * (1.f / 64.f);
    #pragma unroll
    for (int ni = 0; ni < 4; ++ni) {
      float sum = 0.f;
      #pragma unroll
      for (int mi = 0; mi < 4; ++mi)
        #pragma unroll
        for (int rr = 0; rr < 4; ++rr) sum += acc[mi][ni][rr];
      sum += __shfl_xor(sum, 16);
      sum += __shfl_xor(sum, 32);
      if (hi == 0) {
        int cseg = (cc & 3) * 128 + wn * 64 + ni * 16 + lo;
        int h = cseg >> 6, d = cseg & 63;
        int bh = b * 8 + h;
        float lm = sum * lscale;
        if (seg == 0) {
          ql[((size_t)bh * 64 + m) * 64 + d] = lm;
        } else {
          kl[((size_t)bh * 64 + m) * 64 + d] = lm;
          klh[((size_t)bh * 64 + m) * 64 + d] = (_Float16)lm;
        }
      }
    }
  }
}

// ---------------- out-proj via global_load_lds -> f16 lnb ----------------
__global__ __launch_bounds__(256) void k_op_s(
    const _Float16* __restrict__ attb, const _Float16* __restrict__ owT,
    const float* __restrict__ ob, _Float16* __restrict__ lnb) {
  __shared__ _Float16 Abuf[2][128 * 32];
  __shared__ _Float16 Bbuf[2][160 * 32];
  const int t = threadIdx.x;
  const int bid = blockIdx.x;
  const int xcd = bid & 7, slot = bid >> 3;
  const int pj = slot / 5, cc = slot % 5;
  const int p = pj * 8 + xcd;
  const int r0 = p * 128, c0 = cc * 160;

  const int w = t >> 6, l = t & 63;
  const int kslot = (l & 3) ^ ((l >> 3) & 3);
  const _Float16* gA[2];
  #pragma unroll
  for (int s = 0; s < 2; ++s) {
    int mar = 16 * w + (l >> 2) + 64 * s;
    gA[s] = attb + (size_t)(r0 + mar) * 512 + kslot * 8;
  }
  const _Float16* gB[3];
  #pragma unroll
  for (int s = 0; s < 3; ++s) {
    int rb = 16 * w + (l >> 2) + 64 * s;
    if (rb > 159) rb = 159;
    gB[s] = owT + (size_t)(c0 + rb) * 512 + kslot * 8;
  }

  const int lo = t & 15, hi = (t >> 4) & 3;
  const int wm = w >> 1, wn = w & 1;
  const int sl = hi ^ ((lo >> 1) & 3);
  const int roA = (wm * 64 + lo) * 32 + sl * 8;
  const int roB = (wn * 80 + lo) * 32 + sl * 8;

  f32x4 acc[4][5] = {};

  auto STAGE = [&](int buf, int ck) {
    const int kn = ck << 5;
    _Float16* Ad = &Abuf[buf][512 * w];
    _Float16* Bd = &Bbuf[buf][512 * w];
    gl_lds16(gA[0] + kn, Ad);
    gl_lds16(gA[1] + kn, Ad + 2048);
    gl_lds16(gB[0] + kn, Bd);
    gl_lds16(gB[1] + kn, Bd + 2048);
    if (w < 2) gl_lds16(gB[2] + kn, Bd + 4096);
  };

  STAGE(0, 0);
  __syncthreads();

  for (int ck = 0; ck < 16; ++ck) {
    const int cur = ck & 1;
    if (ck + 1 < 16) STAGE(cur ^ 1, ck + 1);
    half8 af[4], bf[5];
    #pragma unroll
    for (int mi = 0; mi < 4; ++mi)
      af[mi] = *reinterpret_cast<const half8*>(&Abuf[cur][roA + mi * 512]);
    #pragma unroll
    for (int ni = 0; ni < 5; ++ni)
      bf[ni] = *reinterpret_cast<const half8*>(&Bbuf[cur][roB + ni * 512]);
    #pragma unroll
    for (int mi = 0; mi < 4; ++mi)
      #pragma unroll
      for (int ni = 0; ni < 5; ++ni)
        acc[mi][ni] = __builtin_amdgcn_mfma_f32_16x16x32_f16(af[mi], bf[ni], acc[mi][ni], 0, 0, 0);
    __syncthreads();
  }

  #pragma unroll
  for (int ni = 0; ni < 5; ++ni) {
    int col = c0 + wn * 80 + ni * 16 + lo;
    float bv = ob[col];
    #pragma unroll
    for (int mi = 0; mi < 4; ++mi)
      #pragma unroll
      for (int rr = 0; rr < 4; ++rr) {
        int row = r0 + wm * 64 + mi * 16 + hi * 4 + rr;
        lnb[(size_t)row * 800 + col] = (_Float16)(acc[mi][ni][rr] + bv);
      }
  }
}

// ---------------- a2 + global max row/col sums ----------------
__global__ __launch_bounds__(64) void k_a2(
    const float* __restrict__ ql, const float* __restrict__ kl,
    float* __restrict__ a2, float* __restrict__ scal) {
  __shared__ float sp[64 * 65];
  const int bh = blockIdx.x, t = threadIdx.x;
  const float* qr = ql + ((size_t)bh * 64 + t) * 64;
  const float* kb = kl + (size_t)bh * 4096;
  float mx = -1e30f;
  for (int c = 0; c < 64; ++c) {
    float acc = 0.f;
    #pragma unroll 8
    for (int dd = 0; dd < 64; ++dd) acc = fmaf(qr[dd], kb[c * 64 + dd], acc);
    sp[t * 65 + c] = acc;
    mx = fmaxf(mx, acc);
  }
  float sum = 0.f;
  for (int c = 0; c < 64; ++c) {
    float e = expf(sp[t * 65 + c] - mx);
    sp[t * 65 + c] = e;
    sum += e;
  }
  float inv = 1.f / sum;
  float rs = 0.f;
  for (int c = 0; c < 64; ++c) {
    float p = sp[t * 65 + c] * inv;
    sp[t * 65 + c] = p;
    a2[(size_t)bh * 4096 + t * 64 + c] = p;
    rs += p;
  }
  atomicMax(reinterpret_cast<int*>(scal), __float_as_int(rs));
  __syncthreads();
  float cs = 0.f;
  for (int r = 0; r < 64; ++r) cs += sp[r * 65 + t];
  atomicMax(reinterpret_cast<int*>(scal) + 1, __float_as_int(cs));
}

// ---------------- fused a3 softmax + a3@v ----------------
__global__ __launch_bounds__(256) void k_a3v(
    const float* __restrict__ ql, const _Float16* __restrict__ kT,
    const _Float16* __restrict__ vx, float* __restrict__ a3v) {
  __shared__ float sq[64];
  __shared__ float sP[4096];
  __shared__ float red[4];
  __shared__ float red2[4][64];
  const int t = threadIdx.x;
  const int m = blockIdx.x, bh = blockIdx.y;
  if (t < 64) sq[t] = ql[((size_t)bh * 64 + m) * 64 + t];
  __syncthreads();
  const _Float16* kb = kT + (size_t)bh * 262144;
  float sc[16];
  #pragma unroll
  for (int i = 0; i < 16; ++i) sc[i] = 0.f;
  for (int dd = 0; dd < 64; ++dd) {
    float qv = sq[dd];
    const half8* kr = reinterpret_cast<const half8*>(kb + (size_t)dd * 4096 + t * 16);
    half8 k0 = kr[0], k1 = kr[1];
    #pragma unroll
    for (int i = 0; i < 8; ++i) sc[i] = fmaf(qv, (float)k0[i], sc[i]);
    #pragma unroll
    for (int i = 0; i < 8; ++i) sc[8 + i] = fmaf(qv, (float)k1[i], sc[8 + i]);
  }
  float mx = sc[0];
  #pragma unroll
  for (int i = 1; i < 16; ++i) mx = fmaxf(mx, sc[i]);
  #pragma unroll
  for (int o = 32; o; o >>= 1) mx = fmaxf(mx, __shfl_xor(mx, o));
  if ((t & 63) == 0) red[t >> 6] = mx;
  __syncthreads();
  mx = fmaxf(fmaxf(red[0], red[1]), fmaxf(red[2], red[3]));
  __syncthreads();
  float sum = 0.f;
  #pragma unroll
  for (int i = 0; i < 16; ++i) {
    sc[i] = expf(sc[i] - mx);
    sum += sc[i];
  }
  #pragma unroll
  for (int o = 32; o; o >>= 1) sum += __shfl_xor(sum, o);
  if ((t & 63) == 0) red[t >> 6] = sum;
  __syncthreads();
  sum = red[0] + red[1] + red[2] + red[3];
  float inv = 1.f / sum;
  #pragma unroll
  for (int i = 0; i < 16; ++i) sP[t * 16 + i] = sc[i] * inv;
  __syncthreads();
  const int seg = t >> 6, l = t & 63;
  const int nl = l >> 3, dblk = (l & 7) * 8;
  const _Float16* vb = vx + (size_t)bh * 262144;
  float acc8[8] = {};
  for (int it = 0; it < 128; ++it) {
    int n8 = seg * 1024 + it * 8;
    half8 vv = *reinterpret_cast<const half8*>(&vb[(size_t)(n8 + nl) * 64 + dblk]);
    float pc = sP[n8 + nl];
    #pragma unroll
    for (int u = 0; u < 8; ++u) acc8[u] = fmaf(pc, (float)vv[u], acc8[u]);
  }
  #pragma unroll
  for (int off = 8; off <= 32; off <<= 1)
    #pragma unroll
    for (int u = 0; u < 8; ++u) acc8[u] += __shfl_xor(acc8[u], off);
  if (nl == 0) {
    #pragma unroll
    for (int u = 0; u < 8; ++u) red2[seg][dblk + u] = acc8[u];
  }
  __syncthreads();
  if (seg == 0)
    a3v[((size_t)bh * 64 + m) * 64 + l] = red2[0][l] + red2[1][l] + red2[2][l] + red2[3][l];
}

// ---------------- Moore-Penrose pinv + fused w2t ----------------
__global__ __launch_bounds__(256) void k_pinv(
    const float* __restrict__ a2g, const float* __restrict__ scal,
    const float* __restrict__ a3vg, _Float16* __restrict__ w2t) {
  __shared__ float z[64 * 68];
  __shared__ float az[64 * 68];
  __shared__ float tb[64 * 68];
  const int bh = blockIdx.x, t = threadIdx.x;
  const int r0 = (t >> 4) << 2, c0 = (t & 15) << 2;
  const float* ag = a2g + (size_t)bh * 4096;
  const float denom = 1.f / (scal[0] * scal[1]);
  #pragma unroll
  for (int i = 0; i < 4; ++i)
    #pragma unroll
    for (int j = 0; j < 4; ++j)
      z[(r0 + i) * 68 + c0 + j] = ag[(c0 + j) * 64 + r0 + i] * denom;
  __syncthreads();
  float reg[4][4], val[4][4];
  for (int it = 0; it < 6; ++it) {
    mm16v<64, 68>(ag, z, r0, c0, reg);
    #pragma unroll
    for (int i = 0; i < 4; ++i)
      #pragma unroll
      for (int j = 0; j < 4; ++j) az[(r0 + i) * 68 + c0 + j] = reg[i][j];
    __syncthreads();
    mm16v<68, 68>(az, az, r0, c0, reg);
    #pragma unroll
    for (int i = 0; i < 4; ++i)
      #pragma unroll
      for (int j = 0; j < 4; ++j)
        tb[(r0 + i) * 68 + c0 + j] = 7.f * az[(r0 + i) * 68 + c0 + j] - reg[i][j];
    __syncthreads();
    mm16v<68, 68>(az, tb, r0, c0, reg);
    #pragma unroll
    for (int i = 0; i < 4; ++i)
      #pragma unroll
      for (int j = 0; j < 4; ++j)
        val[i][j] = 15.f * az[(r0 + i) * 68 + c0 + j] - reg[i][j];
    __syncthreads();
    #pragma unroll
    for (int i = 0; i < 4; ++i)
      #pragma unroll
      for (int j = 0; j < 4; ++j) tb[(r0 + i) * 68 + c0 + j] = val[i][j];
    __syncthreads();
    mm16v<68, 68>(z, tb, r0, c0, reg);
    #pragma unroll
    for (int i = 0; i < 4; ++i)
      #pragma unroll
      for (int j = 0; j < 4; ++j)
        val[i][j] = 0.25f * (13.f * z[(r0 + i) * 68 + c0 + j] - reg[i][j]);
    __syncthreads();
    #pragma unroll
    for (int i = 0; i < 4; ++i)
      #pragma unroll
      for (int j = 0; j < 4; ++j) z[(r0 + i) * 68 + c0 + j] = val[i][j];
    __syncthreads();
  }
  mm16v<68, 64>(z, a3vg + (size_t)bh * 4096, r0, c0, reg);
  #pragma unroll
  for (int i = 0; i < 4; ++i)
    #pragma unroll
    for (int j = 0; j < 4; ++j)
      w2t[(size_t)bh * 4096 + (c0 + j) * 64 + (r0 + i)] = (_Float16)reg[i][j];
}

// ------- fused MFMA combine ------------
__global__ __launch_bounds__(256) void k_combine_m(
    const _Float16* __restrict__ qx, const _Float16* __restrict__ klh,
    const _Float16* __restrict__ w2t, const _Float16* __restrict__ vx,
    const float* __restrict__ rw, _Float16* __restrict__ att) {
  __shared__ _Float16 sP[64 * 72];
  __shared__ _Float16 sVT[64 * 104];
  __shared__ _Float16 sT[64 * 104];
  __shared__ float sR[33];
  const int t = threadIdx.x, w = t >> 6, lo = t & 15, hi = (t >> 4) & 3;
  const int n0 = blockIdx.x * 64;
  const int h = blockIdx.y, b = blockIdx.z, bh = b * 8 + h;
  if (t < 33) sR[t] = rw[h * 33 + t];
  __syncthreads();
  const _Float16* vb = vx + (size_t)bh * 262144;
  #pragma unroll
  for (int u = 0; u < 24; ++u) {
    int e = t + u * 256;
    int r = e >> 6, d = e & 63;
    int nn = n0 - 16 + r;
    sVT[d * 104 + r] = ((unsigned)nn < 4096u) ? vb[(size_t)nn * 64 + d] : (_Float16)0.f;
  }
  #pragma unroll
  for (int u = 0; u < 24; ++u) {
    int e = t + u * 256;
    int r = e % 96, i = e / 96;
    int j = r - i;
    sT[i * 104 + r] = (j >= 0 && j < 33) ? (_Float16)sR[j] : (_Float16)0.f;
  }
  f32x4 sa[4] = {};
  const _Float16* qp = qx + ((size_t)bh * 4096 + n0 + w * 16 + lo) * 64 + 8 * hi;
  const _Float16* klp = klh + (size_t)bh * 4096;
  #pragma unroll
  for (int c = 0; c < 2; ++c) {
    half8 a = *reinterpret_cast<const half8*>(qp + 32 * c);
    #pragma unroll
    for (int ct = 0; ct < 4; ++ct) {
      half8 bf = *reinterpret_cast<const half8*>(klp + (size_t)(ct * 16 + lo) * 64 + 8 * hi + 32 * c);
      sa[ct] = __builtin_amdgcn_mfma_f32_16x16x32_f16(a, bf, sa[ct], 0, 0, 0);
    }
  }
  #pragma unroll
  for (int r = 0; r < 4; ++r) {
    float mx = fmaxf(fmaxf(sa[0][r], sa[1][r]), fmaxf(sa[2][r], sa[3][r]));
    #pragma unroll
    for (int o = 8; o; o >>= 1) mx = fmaxf(mx, __shfl_xor(mx, o));
    float e0 = expf(sa[0][r] - mx), e1 = expf(sa[1][r] - mx);
    float e2 = expf(sa[2][r] - mx), e3 = expf(sa[3][r] - mx);
    float sm = e0 + e1 + e2 + e3;
    #pragma unroll
    for (int o = 8; o; o >>= 1) sm += __shfl_xor(sm, o);
    float inv = 1.f / sm;
    int row = w * 16 + hi * 4 + r;
    sP[row * 72 + lo] = (_Float16)(e0 * inv);
    sP[row * 72 + 16 + lo] = (_Float16)(e1 * inv);
    sP[row * 72 + 32 + lo] = (_Float16)(e2 * inv);
    sP[row * 72 + 48 + lo] = (_Float16)(e3 * inv);
  }
  __syncthreads();
  f32x4 ao[4] = {};
  const _Float16* w2p = w2t + (size_t)bh * 4096;
  #pragma unroll
  for (int c = 0; c < 2; ++c) {
    half8 a = *reinterpret_cast<const half8*>(&sP[(w * 16 + lo) * 72 + 8 * hi + 32 * c]);
    #pragma unroll
    for (int ct = 0; ct < 4; ++ct) {
      half8 bf = *reinterpret_cast<const half8*>(w2p + (size_t)(ct * 16 + lo) * 64 + 8 * hi + 32 * c);
      ao[ct] = __builtin_amdgcn_mfma_f32_16x16x32_f16(a, bf, ao[ct], 0, 0, 0);
    }
  }
  #pragma unroll
  for (int c = 0; c < 3; ++c) {
    half8 a = *reinterpret_cast<const half8*>(&sT[(w * 16 + lo) * 104 + 8 * hi + 32 * c]);
    #pragma unroll
    for (int ct = 0; ct < 4; ++ct) {
      half8 bf = *reinterpret_cast<const half8*>(&sVT[(ct * 16 + lo) * 104 + 8 * hi + 32 * c]);
      ao[ct] = __builtin_amdgcn_mfma_f32_16x16x32_f16(a, bf, ao[ct], 0, 0, 0);
    }
  }
  _Float16* ab = att + ((size_t)b * 4096) * 512 + (size_t)h * 64;
  #pragma unroll
  for (int ct = 0; ct < 4; ++ct)
    #pragma unroll
    for (int r = 0; r < 4; ++r) {
      int n = n0 + w * 16 + hi * 4 + r;
      ab[(size_t)n * 512 + ct * 16 + lo] = (_Float16)ao[ct][r];
    }
}

// ---------------- fused LayerNorm + head MFMA ----------------
__global__ __launch_bounds__(256) void k_lnhead(
    const _Float16* __restrict__ ln, const _Float16* __restrict__ hwh,
    const float* __restrict__ g, const float* __restrict__ bb,
    const float* __restrict__ hb, float* __restrict__ out) {
  const int t = threadIdx.x, w = t >> 6, lo = t & 15, hi = (t >> 4) & 3;
  const int row0 = blockIdx.x * 64 + w * 16;
  const _Float16* ap = ln + (size_t)(row0 + lo) * 800 + 8 * hi;
  float s1 = 0.f, s2 = 0.f;
  #pragma unroll 5
  for (int k = 0; k < 800; k += 32) {
    half8 a = *reinterpret_cast<const half8*>(ap + k);
    #pragma unroll
    for (int u = 0; u < 8; ++u) {
      float x = (float)a[u];
      s1 += x;
      s2 = fmaf(x, x, s2);
    }
  }
  s1 += __shfl_xor(s1, 16); s1 += __shfl_xor(s1, 32);
  s2 += __shfl_xor(s2, 16); s2 += __shfl_xor(s2, 32);
  float mean = s1 * (1.f / 800.f);
  float var = s2 * (1.f / 800.f) - mean * mean;
  float rstd = rsqrtf(var + LN_EPS_C);
  const _Float16* bp = hwh + (size_t)lo * 800 + 8 * hi;
  f32x4 acc = {};
  #pragma unroll 5
  for (int k = 0; k < 800; k += 32) {
    half8 a = *reinterpret_cast<const half8*>(ap + k);
    half8 an;
    #pragma unroll
    for (int u = 0; u < 8; ++u) {
      int kk = k + 8 * hi + u;
      float x = ((float)a[u] - mean) * rstd * g[kk] + bb[kk];
      an[u] = (_Float16)x;
    }
    half8 b = *reinterpret_cast<const half8*>(bp + k);
    acc = __builtin_amdgcn_mfma_f32_16x16x32_f16(an, b, acc, 0, 0, 0);
  }
  float bv = hb[lo];
  #pragma unroll
  for (int r = 0; r < 4; ++r) {
    int row = row0 + hi * 4 + r;
    out[(size_t)row * 16 + lo] = 1.f / (1.f + expf(-(acc[r] + bv)));
  }
}

// ---------------- launcher ----------------
extern "C" void kernel_launch(void* const* d_in, const int* in_sizes, int n_in,
                              void* d_out, int out_size, void* d_ws, size_t ws_size,
                              hipStream_t stream) {
  (void)in_sizes; (void)n_in; (void)out_size; (void)ws_size;
  const float* x     = (const float*)d_in[0];
  const float* w0    = (const float*)d_in[1];
  const float* b0    = (const float*)d_in[2];
  const float* g0    = (const float*)d_in[3];
  const float* be0   = (const float*)d_in[4];
  const float* mu0   = (const float*)d_in[5];
  const float* var0  = (const float*)d_in[6];
  const float* w1    = (const float*)d_in[7];
  const float* b1    = (const float*)d_in[8];
  const float* g1    = (const float*)d_in[9];
  const float* be1   = (const float*)d_in[10];
  const float* mu1   = (const float*)d_in[11];
  const float* var1  = (const float*)d_in[12];
  const float* w2c   = (const float*)d_in[13];
  const float* b2    = (const float*)d_in[14];
  const float* g2    = (const float*)d_in[15];
  const float* be2   = (const float*)d_in[16];
  const float* mu2   = (const float*)d_in[17];
  const float* var2  = (const float*)d_in[18];
  const float* w3    = (const float*)d_in[19];
  const float* b3    = (const float*)d_in[20];
  const float* g3    = (const float*)d_in[21];
  const float* be3   = (const float*)d_in[22];
  const float* mu3   = (const float*)d_in[23];
  const float* var3  = (const float*)d_in[24];
  const float* qkvw  = (const float*)d_in[25];
  const float* outw  = (const float*)d_in[26];
  const float* outbv = (const float*)d_in[27];
  const float* resw  = (const float*)d_in[28];
  const float* lng   = (const float*)d_in[29];
  const float* lnbv  = (const float*)d_in[30];
  const float* headw = (const float*)d_in[31];
  const float* headb = (const float*)d_in[32];

  char* wsb = (char*)d_ws;
  _Float16* h0   = (_Float16*)(wsb + B_H0);
  _Float16* h1   = (_Float16*)(wsb + B_H1);
  _Float16* h2   = (_Float16*)(wsb + B_H2);
  _Float16* qb   = (_Float16*)(wsb + B_Q);
  _Float16* vb   = (_Float16*)(wsb + B_V);
  _Float16* kT   = (_Float16*)(wsb + B_KT);
  _Float16* tok  = (_Float16*)(wsb + B_TOK);
  _Float16* attb = (_Float16*)(wsb + B_ATT);
  _Float16* wp1  = (_Float16*)(wsb + B_WP1);
  _Float16* wp2  = (_Float16*)(wsb + B_WP2);
  _Float16* wp3  = (_Float16*)(wsb + B_WP3);
  _Float16* qkvT = (_Float16*)(wsb + B_QKVT);
  _Float16* owT  = (_Float16*)(wsb + B_OWT);
  _Float16* klh  = (_Float16*)(wsb + B_KLH);
  _Float16* w2t  = (_Float16*)(wsb + B_W2T);
  _Float16* hwh  = (_Float16*)(wsb + B_HWH);
  _Float16* lnb16 = (_Float16*)(wsb + B_LNB);
  _Float16* zpg  = (_Float16*)(wsb + B_ZPG);
  float* ql   = (float*)(wsb + B_QL);
  float* kl   = (float*)(wsb + B_KL);
  float* a2   = (float*)(wsb + B_A2);
  float* a3v  = (float*)(wsb + B_A3V);
  float* scal = (float*)(wsb + B_SCAL);

  k_pack_all<<<dim3(20691), 256, 0, stream>>>(
      w1, w2c, w3, qkvw, outw, headw, wp1, wp2, wp3, qkvT, owT, hwh, scal, (float*)zpg);

  for (int img = 0; img < 4; ++img) {
    k_conv0<<<dim3(256, 4), 256, 0, stream>>>(
        x + (size_t)img * 65536, w0, b0, g0, be0, mu0, var0, h0);
    k_convs<64><<<dim3(512), 256, 0, stream>>>(
        h0, wp1, b1, g1, be1, mu1, var1, h1, 128, 1, zpg);
    k_convs<128><<<dim3(1024), 256, 0, stream>>>(
        h1, wp2, b2, g2, be2, mu2, var2, h2 + (size_t)img * 16777216, 256, 2, zpg);
  }
  k_c3<<<dim3(640), 256, 0, stream>>>(h2, wp3, b3, g3, be3, mu3, var3, tok);
  k_qkv_s<<<dim3(1536), 256, 0, stream>>>(tok, qkvT, qb, kT, vb, ql, kl, klh);
  k_a2<<<dim3(32), 64, 0, stream>>>(ql, kl, a2, scal);
  k_a3v<<<dim3(64, 32), 256, 0, stream>>>(ql, kT, vb, a3v);
  k_pinv<<<dim3(32), 256, 0, stream>>>(a2, scal, a3v, w2t);
  k_combine_m<<<dim3(64, 8, 4), 256, 0, stream>>>(qb, klh, w2t, vb, resw, attb);
  k_op_s<<<dim3(640), 256, 0, stream>>>(attb, owT, outbv, lnb16);
  k_lnhead<<<dim3(256), 256, 0, stream>>>(lnb16, hwh, lng, lnbv, headb, (float*)d_out);
}